// Round 2
// baseline (2787.547 us; speedup 1.0000x reference)
//
#include <hip/hip_runtime.h>
#include <stdint.h>

#define BATCH 64
#define NN 131072
#define NBIN 65536

__device__ __forceinline__ uint32_t rotl32(uint32_t v, int d) { return (v << d) | (v >> (32 - d)); }

// Exact port of JAX threefry2x32 block cipher (jax/_src/prng.py)
__device__ __forceinline__ void threefry2x32(uint32_t k0, uint32_t k1, uint32_t x0, uint32_t x1,
                                             uint32_t& o0, uint32_t& o1) {
  uint32_t ks2 = k0 ^ k1 ^ 0x1BD11BDAu;
  x0 += k0; x1 += k1;
#define TF_R(r) { x0 += x1; x1 = rotl32(x1, r); x1 ^= x0; }
  TF_R(13) TF_R(15) TF_R(26) TF_R(6)
  x0 += k1;  x1 += ks2 + 1u;
  TF_R(17) TF_R(29) TF_R(16) TF_R(24)
  x0 += ks2; x1 += k0 + 2u;
  TF_R(13) TF_R(15) TF_R(26) TF_R(6)
  x0 += k0;  x1 += k1 + 3u;
  TF_R(17) TF_R(29) TF_R(16) TF_R(24)
  x0 += k1;  x1 += ks2 + 4u;
  TF_R(13) TF_R(15) TF_R(26) TF_R(6)
  x0 += ks2; x1 += k0 + 5u;
#undef TF_R
  o0 = x0; o1 = x1;
}

// threefry_partitionable=True (default since JAX 0.4.36/0.5):
// random_bits(key, 32, (N,)) -> bits[i] = o0 ^ o1 of cipher(key, (0, i))  (N < 2^32)
__device__ __forceinline__ uint32_t tf_bits(uint32_t k0, uint32_t k1, uint32_t i) {
  uint32_t o0, o1;
  threefry2x32(k0, k1, 0u, i, o0, o1);
  return o0 ^ o1;
}

// split(key, num) foldlike: child i = cipher(key, (0, i)) (both words = child key data).
// master = key(42) = (0,42). kb = cipher(master, (0,b)).
// _shuffle round 1: key,sub1 = split(kb) -> carried = cipher(kb,(0,0)), sub1 = cipher(kb,(0,1)).
// round 2: sub2 = cipher(carried, (0,1)).
__device__ void batch_round_key(int b, int round, uint32_t& rk0, uint32_t& rk1) {
  uint32_t kb0, kb1;
  threefry2x32(0u, 42u, 0u, (uint32_t)b, kb0, kb1);
  if (round == 1) {
    threefry2x32(kb0, kb1, 0u, 1u, rk0, rk1);
    return;
  }
  uint32_t c0, c1;
  threefry2x32(kb0, kb1, 0u, 0u, c0, c1);
  threefry2x32(c0, c1, 0u, 1u, rk0, rk1);
}

__global__ void hist_kernel(uint32_t* __restrict__ binscan, int round, int batch0) {
  __shared__ uint32_t sk[2];
  int g = blockIdx.y;
  if (threadIdx.x == 0) { uint32_t k0, k1; batch_round_key(batch0 + g, round, k0, k1); sk[0] = k0; sk[1] = k1; }
  __syncthreads();
  uint32_t e = blockIdx.x * blockDim.x + threadIdx.x;  // 0..131071
  uint32_t bits = tf_bits(sk[0], sk[1], e);
  atomicAdd(&binscan[(size_t)g * NBIN + (bits >> 16)], 1u);
}

__global__ __launch_bounds__(1024) void scan_kernel(uint32_t* __restrict__ binscan) {
  int g = blockIdx.x;
  uint32_t* arr = binscan + (size_t)g * NBIN;
  __shared__ uint32_t tmp[1024];
  int tid = threadIdx.x;
  uint32_t running = 0;
  for (int c = 0; c < NBIN; c += 1024) {
    uint32_t v = arr[c + tid];
    tmp[tid] = v;
    __syncthreads();
    for (int off = 1; off < 1024; off <<= 1) {
      uint32_t t = (tid >= off) ? tmp[tid - off] : 0u;
      __syncthreads();
      tmp[tid] += t;
      __syncthreads();
    }
    uint32_t incl = tmp[tid];
    uint32_t total = tmp[1023];
    arr[c + tid] = running + incl - v;  // exclusive prefix
    running += total;
    __syncthreads();
  }
}

__global__ void scatter_kernel(uint32_t* __restrict__ binscan, uint32_t* __restrict__ binned,
                               int round, int batch0) {
  __shared__ uint32_t sk[2];
  int g = blockIdx.y;
  if (threadIdx.x == 0) { uint32_t k0, k1; batch_round_key(batch0 + g, round, k0, k1); sk[0] = k0; sk[1] = k1; }
  __syncthreads();
  uint32_t e = blockIdx.x * blockDim.x + threadIdx.x;
  uint32_t bits = tf_bits(sk[0], sk[1], e);
  uint32_t s = atomicAdd(&binscan[(size_t)g * NBIN + (bits >> 16)], 1u);
  binned[(size_t)g * NN + s] = e;
}

// After scatter, binscan[bin] = inclusive end of bin; start = binscan[bin-1] (or 0).
// Exact stable rank within bin by (key, position); write sorted payload order.
__global__ void finalize_kernel(const uint32_t* __restrict__ binscan, const uint32_t* __restrict__ binned,
                                const uint32_t* __restrict__ Ain, uint32_t* __restrict__ Aout,
                                int round, int batch0, int useAin) {
  __shared__ uint32_t sk[2];
  int g = blockIdx.y;
  if (threadIdx.x == 0) { uint32_t k0, k1; batch_round_key(batch0 + g, round, k0, k1); sk[0] = k0; sk[1] = k1; }
  __syncthreads();
  uint32_t bin = blockIdx.x * blockDim.x + threadIdx.x;  // 0..65535
  const uint32_t* bs = binscan + (size_t)g * NBIN;
  const uint32_t* bn = binned + (size_t)g * NN;
  const uint32_t* ain = Ain ? Ain + (size_t)g * NN : nullptr;
  uint32_t* aout = Aout + (size_t)g * NN;
  uint32_t start = bin ? bs[bin - 1] : 0u;
  uint32_t end = bs[bin];
  for (uint32_t t = start; t < end; ++t) {
    uint32_t e = bn[t];
    uint32_t ke = tf_bits(sk[0], sk[1], e);
    uint32_t rank = 0;
    for (uint32_t u = start; u < end; ++u) {
      if (u == t) continue;
      uint32_t f = bn[u];
      uint32_t kf = tf_bits(sk[0], sk[1], f);
      if (kf < ke || (kf == ke && f < e)) rank++;  // stable: tie-break by position
    }
    uint32_t payload = useAin ? ain[e] : e;
    aout[start + rank] = payload;
  }
}

// One block per batch: count available positives, then scan the final permutation
// backwards selecting the last qp positives and last qn negatives (largest shuffled
// positions = reference's balanced sample), then bitonic-sort 512 indices ascending.
__global__ __launch_bounds__(1024) void select_kernel(const uint32_t* __restrict__ A2,
                                                      const int* __restrict__ posg,
                                                      const int* __restrict__ negg,
                                                      const int* __restrict__ igng,
                                                      int* __restrict__ out, int batch0) {
  const int tid = threadIdx.x;
  const int g = blockIdx.x;
  const int b = batch0 + g;
  const uint32_t* A = A2 + (size_t)g * NN;
  const int* P = posg + (size_t)b * NN;
  const int* Q = negg + (size_t)b * NN;
  const int* I = igng + (size_t)b * NN;
  __shared__ int sel[512];
  __shared__ uint32_t scn[1024];
  __shared__ int sh_np, sh_cp, sh_cn, sh_done;

  int cnt = 0;
  for (int i = tid; i < NN; i += 1024) {
    int p = P[i] != 0, n = Q[i] != 0, ig = I[i] != 0;
    if (((p | n) && !ig) && p) cnt++;
  }
  scn[tid] = (uint32_t)cnt;
  __syncthreads();
  for (int off = 512; off > 0; off >>= 1) {
    if (tid < off) scn[tid] += scn[tid + off];
    __syncthreads();
  }
  if (tid == 0) { sh_np = (int)scn[0]; sh_cp = 0; sh_cn = 0; sh_done = 0; }
  if (tid < 512) sel[tid] = 0;
  __syncthreads();
  const int qp = (sh_np < 128) ? sh_np : 128;
  const int qn = 512 - qp;

  for (int base = NN - 1024; base >= 0; base -= 1024) {
    if (sh_done) break;
    int q = base + tid;
    uint32_t j = A[q];
    int p = P[j] != 0, n = Q[j] != 0, ig = I[j] != 0;
    int cand = ((p | n) && !ig);
    int isPos = cand && p;
    int isNeg = cand && !p;
    int rr = 1023 - tid;  // scan order: highest position first
    scn[rr] = ((uint32_t)isPos << 16) | (uint32_t)isNeg;
    __syncthreads();
    for (int off = 1; off < 1024; off <<= 1) {
      uint32_t t = (rr >= off) ? scn[rr - off] : 0u;
      __syncthreads();
      scn[rr] += t;
      __syncthreads();
    }
    uint32_t incl = scn[rr];
    uint32_t total = scn[1023];
    int posrank = (int)(incl >> 16);
    int negrank = (int)(incl & 0xFFFFu);
    int cp = sh_cp, cn = sh_cn;
    if (isPos && cp + posrank <= qp) sel[cp + posrank - 1] = (int)j;
    if (isNeg && cn + negrank <= qn) sel[qp + cn + negrank - 1] = (int)j;
    __syncthreads();
    if (tid == 0) {
      sh_cp = cp + (int)(total >> 16);
      sh_cn = cn + (int)(total & 0xFFFFu);
      if (sh_cp >= qp && sh_cn >= qn) sh_done = 1;
    }
    __syncthreads();
  }

  // bitonic sort 512 ints ascending
  for (int k = 2; k <= 512; k <<= 1) {
    for (int s = k >> 1; s > 0; s >>= 1) {
      if (tid < 256) {
        int i = ((tid & ~(s - 1)) << 1) | (tid & (s - 1));
        int j2 = i | s;
        bool up = ((i & k) == 0);
        int a = sel[i], c2 = sel[j2];
        if ((a > c2) == up) { sel[i] = c2; sel[j2] = a; }
      }
      __syncthreads();
    }
  }
  if (tid < 512) out[(size_t)b * 512 + tid] = sel[tid];
}

extern "C" void kernel_launch(void* const* d_in, const int* in_sizes, int n_in,
                              void* d_out, int out_size, void* d_ws, size_t ws_size,
                              hipStream_t stream) {
  const int* pos = (const int*)d_in[0];
  const int* neg = (const int*)d_in[1];
  const int* ign = (const int*)d_in[2];
  int* out = (int*)d_out;

  // per-batch ws: binscan 256KB + binned 512KB + A1 512KB + A2 512KB
  size_t perBatch = (size_t)NBIN * 4 + (size_t)NN * 4 * 3;
  int G = (int)(ws_size / perBatch);
  if (G > BATCH) G = BATCH;
  if (G < 1) G = 1;

  uint32_t* binscan = (uint32_t*)d_ws;
  uint32_t* binned = binscan + (size_t)G * NBIN;
  uint32_t* A1 = binned + (size_t)G * NN;
  uint32_t* A2 = A1 + (size_t)G * NN;

  for (int batch0 = 0; batch0 < BATCH; batch0 += G) {
    int Gi = (BATCH - batch0 < G) ? (BATCH - batch0) : G;
    dim3 gridE(NN / 256, Gi);
    dim3 gridB(NBIN / 256, Gi);
    for (int round = 1; round <= 2; ++round) {
      hipMemsetAsync(binscan, 0, (size_t)Gi * NBIN * 4, stream);
      hist_kernel<<<gridE, 256, 0, stream>>>(binscan, round, batch0);
      scan_kernel<<<Gi, 1024, 0, stream>>>(binscan);
      scatter_kernel<<<gridE, 256, 0, stream>>>(binscan, binned, round, batch0);
      if (round == 1)
        finalize_kernel<<<gridB, 256, 0, stream>>>(binscan, binned, nullptr, A1, round, batch0, 0);
      else
        finalize_kernel<<<gridB, 256, 0, stream>>>(binscan, binned, A1, A2, round, batch0, 1);
    }
    select_kernel<<<Gi, 1024, 0, stream>>>(A2, pos, neg, ign, out, batch0);
  }
}

// Round 3
// 1399.611 us; speedup vs baseline: 1.9917x; 1.9917x over previous
//
#include <hip/hip_runtime.h>
#include <stdint.h>

#define BATCH 64
#define NN 131072
#define NBIN 65536
#define EMASK 0xFFFFFu
#define CAP 1024

typedef uint32_t u32;
typedef uint64_t u64;

__device__ __forceinline__ u32 rotl32(u32 v, int d) { return (v << d) | (v >> (32 - d)); }

// Exact port of JAX threefry2x32 block cipher
__device__ __forceinline__ void threefry2x32(u32 k0, u32 k1, u32 x0, u32 x1, u32& o0, u32& o1) {
  u32 ks2 = k0 ^ k1 ^ 0x1BD11BDAu;
  x0 += k0; x1 += k1;
#define TF_R(r) { x0 += x1; x1 = rotl32(x1, r); x1 ^= x0; }
  TF_R(13) TF_R(15) TF_R(26) TF_R(6)
  x0 += k1;  x1 += ks2 + 1u;
  TF_R(17) TF_R(29) TF_R(16) TF_R(24)
  x0 += ks2; x1 += k0 + 2u;
  TF_R(13) TF_R(15) TF_R(26) TF_R(6)
  x0 += k0;  x1 += k1 + 3u;
  TF_R(17) TF_R(29) TF_R(16) TF_R(24)
  x0 += k1;  x1 += ks2 + 4u;
  TF_R(13) TF_R(15) TF_R(26) TF_R(6)
  x0 += ks2; x1 += k0 + 5u;
#undef TF_R
  o0 = x0; o1 = x1;
}

// threefry_partitionable: bits[i] = o0 ^ o1 of cipher(key, (0, i))
__device__ __forceinline__ u32 tf_bits(u32 k0, u32 k1, u32 i) {
  u32 o0, o1;
  threefry2x32(k0, k1, 0u, i, o0, o1);
  return o0 ^ o1;
}

// kb = cipher((0,42),(0,b)); round1 sub = cipher(kb,(0,1));
// round2 sub = cipher(cipher(kb,(0,0)),(0,1))
__device__ void batch_round_key(int b, int round, u32& rk0, u32& rk1) {
  u32 kb0, kb1;
  threefry2x32(0u, 42u, 0u, (u32)b, kb0, kb1);
  if (round == 1) { threefry2x32(kb0, kb1, 0u, 1u, rk0, rk1); return; }
  u32 c0, c1;
  threefry2x32(kb0, kb1, 0u, 0u, c0, c1);
  threefry2x32(c0, c1, 0u, 1u, rk0, rk1);
}

__global__ void hist_kernel(u32* __restrict__ binscan, int batch0) {
  __shared__ u32 sk[2];
  int g = blockIdx.y;
  if (threadIdx.x == 0) { u32 k0, k1; batch_round_key(batch0 + g, 1, k0, k1); sk[0] = k0; sk[1] = k1; }
  __syncthreads();
  u32 e = blockIdx.x * blockDim.x + threadIdx.x;
  u32 bits = tf_bits(sk[0], sk[1], e);
  atomicAdd(&binscan[(size_t)g * NBIN + (bits >> 16)], 1u);
}

__global__ __launch_bounds__(1024) void scan_kernel(u32* __restrict__ binscan) {
  int g = blockIdx.x;
  u32* arr = binscan + (size_t)g * NBIN;
  __shared__ u32 tmp[1024];
  int tid = threadIdx.x;
  u32 running = 0;
  for (int c = 0; c < NBIN; c += 1024) {
    u32 v = arr[c + tid];
    tmp[tid] = v;
    __syncthreads();
    for (int off = 1; off < 1024; off <<= 1) {
      u32 t = (tid >= off) ? tmp[tid - off] : 0u;
      __syncthreads();
      tmp[tid] += t;
      __syncthreads();
    }
    u32 incl = tmp[tid];
    u32 total = tmp[1023];
    arr[c + tid] = running + incl - v;  // exclusive prefix
    running += total;
    __syncthreads();
  }
}

// Counting-sort scatter; fuses the (coalesced) candidate-label read and packs
// label into bits 20-21 of the binned value so no later kernel needs random
// gathers of the flag arrays.
__global__ void scatter_kernel(u32* __restrict__ binscan, u32* __restrict__ binned,
                               const int* __restrict__ posg, const int* __restrict__ negg,
                               const int* __restrict__ igng, int batch0) {
  __shared__ u32 sk[2];
  int g = blockIdx.y;
  int b = batch0 + g;
  if (threadIdx.x == 0) { u32 k0, k1; batch_round_key(b, 1, k0, k1); sk[0] = k0; sk[1] = k1; }
  __syncthreads();
  u32 e = blockIdx.x * blockDim.x + threadIdx.x;
  int p = posg[(size_t)b * NN + e] != 0;
  int n = negg[(size_t)b * NN + e] != 0;
  int ig = igng[(size_t)b * NN + e] != 0;
  u32 label = ((p | n) && !ig) ? (p ? 1u : 2u) : 0u;
  u32 bits = tf_bits(sk[0], sk[1], e);
  u32 s = atomicAdd(&binscan[(size_t)g * NBIN + (bits >> 16)], 1u);
  binned[(size_t)g * NN + s] = e | (label << 20);
}

// One thread per bin: exact stable within-bin rank -> p1 = round-1 rank of e.
// Writes EL[p1] = e|label (contiguous runs, low write amplification), and
// histograms k2 = key2(p1) for positive / negative candidates.
__global__ void rankk2_kernel(const u32* __restrict__ binscan, const u32* __restrict__ binned,
                              u32* __restrict__ EL, u32* __restrict__ posh, u32* __restrict__ negh,
                              int batch0) {
  __shared__ u32 sk1[2], sk2[2];
  int g = blockIdx.y;
  if (threadIdx.x == 0) {
    u32 a, b2;
    batch_round_key(batch0 + g, 1, a, b2); sk1[0] = a; sk1[1] = b2;
    batch_round_key(batch0 + g, 2, a, b2); sk2[0] = a; sk2[1] = b2;
  }
  __syncthreads();
  u32 bin = blockIdx.x * blockDim.x + threadIdx.x;
  const u32* bs = binscan + (size_t)g * NBIN;
  const u32* bn = binned + (size_t)g * NN;
  u32* el = EL + (size_t)g * NN;
  u32* ph = posh + (size_t)g * 256;
  u32* nh = negh + (size_t)g * NBIN;
  u32 start = bin ? bs[bin - 1] : 0u;
  u32 end = bs[bin];
  u32 s = end - start;
  if (s == 0) return;
  if (s <= 16) {  // fast path: Poisson(2) occupancy, s>16 essentially never
    u32 vv[16], kk[16];
    for (u32 i = 0; i < s; i++) { vv[i] = bn[start + i]; kk[i] = tf_bits(sk1[0], sk1[1], vv[i] & EMASK); }
    for (u32 i = 0; i < s; i++) {
      u32 ke = kk[i], e = vv[i] & EMASK, r = 0;
      for (u32 j = 0; j < s; j++) {
        if (j == i) continue;
        u32 f = vv[j] & EMASK;
        if (kk[j] < ke || (kk[j] == ke && f < e)) r++;
      }
      u32 p1 = start + r;
      el[p1] = vv[i];
      u32 label = vv[i] >> 20;
      if (label) {
        u32 k2 = tf_bits(sk2[0], sk2[1], p1);
        if (label == 1) atomicAdd(&ph[k2 >> 24], 1u);
        else atomicAdd(&nh[k2 >> 16], 1u);
      }
    }
  } else {  // exact fallback, no local arrays
    for (u32 t = start; t < end; t++) {
      u32 v = bn[t]; u32 e = v & EMASK;
      u32 ke = tf_bits(sk1[0], sk1[1], e); u32 r = 0;
      for (u32 u2 = start; u2 < end; u2++) {
        if (u2 == t) continue;
        u32 f = bn[u2] & EMASK;
        u32 kf = tf_bits(sk1[0], sk1[1], f);
        if (kf < ke || (kf == ke && f < e)) r++;
      }
      u32 p1 = start + r;
      el[p1] = v;
      u32 label = v >> 20;
      if (label) {
        u32 k2 = tf_bits(sk2[0], sk2[1], p1);
        if (label == 1) atomicAdd(&ph[k2 >> 24], 1u);
        else atomicAdd(&nh[k2 >> 16], 1u);
      }
    }
  }
}

// Per batch: qp = min(128, #pos-candidates), qn = 512-qp; find threshold bins
// tp (over posh, 8-bit bins) and tn (over negh, 16-bit bins) s.t. suffix count >= q.
__global__ __launch_bounds__(1024) void threshold_kernel(const u32* __restrict__ posh,
                                                         const u32* __restrict__ negh,
                                                         u32* __restrict__ params) {
  int g = blockIdx.x;
  int tid = threadIdx.x;
  __shared__ u32 red[256];
  __shared__ u32 part[1024];
  const u32* ph = posh + (size_t)g * 256;
  const u32* nh = negh + (size_t)g * NBIN;
  if (tid < 256) red[tid] = ph[tid];
  u32 s = 0;
  for (int j = 0; j < 64; ++j) s += nh[tid * 64 + j];
  part[tid] = s;
  __syncthreads();
  if (tid == 0) {
    u32 np = 0;
    for (int i = 0; i < 256; i++) np += red[i];
    u32 qp = np < 128 ? np : 128;
    u32 qn = 512 - qp;
    u32 tp = 256;
    if (qp > 0) {
      u32 cum = 0;
      for (int b = 255; b >= 0; b--) { cum += red[b]; if (cum >= qp) { tp = (u32)b; break; } }
    }
    u32 tn = 0, cum = 0; int found = 0;
    for (int p = 1023; p >= 0 && !found; p--) {
      if (cum + part[p] >= qn) {
        for (int b2 = 63; b2 >= 0; b2--) {
          cum += nh[p * 64 + b2];
          if (cum >= qn) { tn = (u32)(p * 64 + b2); found = 1; break; }
        }
      } else cum += part[p];
    }
    u32* pr = params + (size_t)g * 4;
    pr[0] = tp; pr[1] = tn; pr[2] = qp; pr[3] = qn;
  }
}

// Coalesced pass over EL: recompute k2 from p1, collect threshold survivors.
__global__ void collect_kernel(const u32* __restrict__ EL, const u32* __restrict__ params,
                               u32* __restrict__ cnt, u64* __restrict__ poskey, u32* __restrict__ posval,
                               u64* __restrict__ negkey, u32* __restrict__ negval, int batch0) {
  __shared__ u32 sk[2];
  __shared__ u32 sp[2];
  int g = blockIdx.y;
  if (threadIdx.x == 0) {
    u32 k0, k1; batch_round_key(batch0 + g, 2, k0, k1); sk[0] = k0; sk[1] = k1;
    const u32* pr = params + (size_t)g * 4; sp[0] = pr[0]; sp[1] = pr[1];
  }
  __syncthreads();
  u32 p1 = blockIdx.x * blockDim.x + threadIdx.x;
  u32 val = EL[(size_t)g * NN + p1];
  u32 label = val >> 20;
  if (!label) return;
  u32 k2 = tf_bits(sk[0], sk[1], p1);
  if (label == 1) {
    if ((k2 >> 24) >= sp[0]) {
      u32 s = atomicAdd(&cnt[(size_t)g * 2], 1u);
      if (s < CAP) { poskey[(size_t)g * CAP + s] = ((u64)k2 << 32) | p1; posval[(size_t)g * CAP + s] = val; }
    }
  } else {
    if ((k2 >> 16) >= sp[1]) {
      u32 s = atomicAdd(&cnt[(size_t)g * 2 + 1], 1u);
      if (s < CAP) { negkey[(size_t)g * CAP + s] = ((u64)k2 << 32) | p1; negval[(size_t)g * CAP + s] = val; }
    }
  }
}

// Per batch: exact top-qp / top-qn by (k2,p1) desc over collected, then 512
// ascending index sort -> output.
__global__ __launch_bounds__(1024) void select_final_kernel(const u32* __restrict__ params,
                                                            const u32* __restrict__ cnt,
                                                            const u64* __restrict__ poskey,
                                                            const u32* __restrict__ posval,
                                                            const u64* __restrict__ negkey,
                                                            const u32* __restrict__ negval,
                                                            int* __restrict__ out, int batch0) {
  int g = blockIdx.x, tid = threadIdx.x, b = batch0 + g;
  __shared__ u64 skey[1024];
  __shared__ u32 sval[1024];
  __shared__ int sel[512];
  const u32* pr = params + (size_t)g * 4;
  u32 qp = pr[2], qn = pr[3];
  u32 cp = cnt[(size_t)g * 2]; if (cp > CAP) cp = CAP;
  u32 cn = cnt[(size_t)g * 2 + 1]; if (cn > CAP) cn = CAP;
  if (tid < 512) sel[tid] = 0;

  // positives: sort descending by (k2,p1) (keys unique: p1 distinct)
  skey[tid] = (tid < (int)cp) ? poskey[(size_t)g * CAP + tid] : 0ull;
  sval[tid] = (tid < (int)cp) ? posval[(size_t)g * CAP + tid] : 0u;
  __syncthreads();
  for (int k = 2; k <= 1024; k <<= 1)
    for (int s = k >> 1; s > 0; s >>= 1) {
      if (tid < 512) {
        int i = ((tid & ~(s - 1)) << 1) | (tid & (s - 1));
        int j = i | s;
        bool up = ((i & k) == 0);
        if ((skey[i] < skey[j]) == up) {
          u64 tk = skey[i]; skey[i] = skey[j]; skey[j] = tk;
          u32 tv = sval[i]; sval[i] = sval[j]; sval[j] = tv;
        }
      }
      __syncthreads();
    }
  if (tid < (int)qp) sel[tid] = (int)(sval[tid] & EMASK);
  __syncthreads();

  // negatives
  skey[tid] = (tid < (int)cn) ? negkey[(size_t)g * CAP + tid] : 0ull;
  sval[tid] = (tid < (int)cn) ? negval[(size_t)g * CAP + tid] : 0u;
  __syncthreads();
  for (int k = 2; k <= 1024; k <<= 1)
    for (int s = k >> 1; s > 0; s >>= 1) {
      if (tid < 512) {
        int i = ((tid & ~(s - 1)) << 1) | (tid & (s - 1));
        int j = i | s;
        bool up = ((i & k) == 0);
        if ((skey[i] < skey[j]) == up) {
          u64 tk = skey[i]; skey[i] = skey[j]; skey[j] = tk;
          u32 tv = sval[i]; sval[i] = sval[j]; sval[j] = tv;
        }
      }
      __syncthreads();
    }
  if (tid < (int)qn) sel[qp + tid] = (int)(sval[tid] & EMASK);
  __syncthreads();

  // ascending sort of 512 selected indices
  for (int k = 2; k <= 512; k <<= 1)
    for (int s = k >> 1; s > 0; s >>= 1) {
      if (tid < 256) {
        int i = ((tid & ~(s - 1)) << 1) | (tid & (s - 1));
        int j = i | s;
        bool up = ((i & k) == 0);
        int a = sel[i], c = sel[j];
        if ((a > c) == up) { sel[i] = c; sel[j] = a; }
      }
      __syncthreads();
    }
  if (tid < 512) out[(size_t)b * 512 + tid] = sel[tid];
}

extern "C" void kernel_launch(void* const* d_in, const int* in_sizes, int n_in,
                              void* d_out, int out_size, void* d_ws, size_t ws_size,
                              hipStream_t stream) {
  const int* pos = (const int*)d_in[0];
  const int* neg = (const int*)d_in[1];
  const int* ign = (const int*)d_in[2];
  int* out = (int*)d_out;

  // per-batch ws bytes: bufs 24KB + binscan 256KB + negh 256KB + binned 512KB
  //                   + EL 512KB + posh 1KB + params/cnt
  size_t perBatch = (size_t)CAP * (8 + 8 + 4 + 4) + ((size_t)NBIN * 2 + (size_t)NN * 2) * 4 + (256 + 4 + 2) * 4;
  int G = (int)(ws_size / perBatch);
  if (G > BATCH) G = BATCH;
  if (G < 1) G = 1;

  char* p = (char*)d_ws;
  u64* poskey = (u64*)p;            p += (size_t)G * CAP * 8;
  u64* negkey = (u64*)p;            p += (size_t)G * CAP * 8;
  u32* posval = (u32*)p;            p += (size_t)G * CAP * 4;
  u32* negval = (u32*)p;            p += (size_t)G * CAP * 4;
  u32* binscan = (u32*)p;           p += (size_t)G * NBIN * 4;
  u32* negh = (u32*)p;              p += (size_t)G * NBIN * 4;
  u32* binned = (u32*)p;            p += (size_t)G * NN * 4;
  u32* EL = (u32*)p;                p += (size_t)G * NN * 4;
  u32* posh = (u32*)p;              p += (size_t)G * 256 * 4;
  u32* params = (u32*)p;            p += (size_t)G * 4 * 4;
  u32* cnt = (u32*)p;               p += (size_t)G * 2 * 4;

  for (int batch0 = 0; batch0 < BATCH; batch0 += G) {
    int Gi = (BATCH - batch0 < G) ? (BATCH - batch0) : G;
    dim3 gridE(NN / 256, Gi);
    dim3 gridB(NBIN / 256, Gi);
    hipMemsetAsync(binscan, 0, (size_t)Gi * NBIN * 4, stream);
    hipMemsetAsync(negh, 0, (size_t)Gi * NBIN * 4, stream);
    hipMemsetAsync(posh, 0, (size_t)Gi * 256 * 4, stream);
    hipMemsetAsync(cnt, 0, (size_t)Gi * 2 * 4, stream);
    hist_kernel<<<gridE, 256, 0, stream>>>(binscan, batch0);
    scan_kernel<<<Gi, 1024, 0, stream>>>(binscan);
    scatter_kernel<<<gridE, 256, 0, stream>>>(binscan, binned, pos, neg, ign, batch0);
    rankk2_kernel<<<gridB, 256, 0, stream>>>(binscan, binned, EL, posh, negh, batch0);
    threshold_kernel<<<Gi, 1024, 0, stream>>>(posh, negh, params);
    collect_kernel<<<gridE, 256, 0, stream>>>(EL, params, cnt, poskey, posval, negkey, negval, batch0);
    select_final_kernel<<<Gi, 1024, 0, stream>>>(params, cnt, poskey, posval, negkey, negval, out, batch0);
  }
}

// Round 4
// 984.047 us; speedup vs baseline: 2.8327x; 1.4223x over previous
//
#include <hip/hip_runtime.h>
#include <stdint.h>

#define BATCH 64
#define NN 131072
#define NCOARSE 256
#define SLOT 1024
#define CHUNK 4096
#define EMASK17 0x1FFFFu
#define CAP 1024

typedef uint32_t u32;
typedef uint64_t u64;

__device__ __forceinline__ u32 rotl32(u32 v, int d) { return (v << d) | (v >> (32 - d)); }

// Exact port of JAX threefry2x32 block cipher
__device__ __forceinline__ void threefry2x32(u32 k0, u32 k1, u32 x0, u32 x1, u32& o0, u32& o1) {
  u32 ks2 = k0 ^ k1 ^ 0x1BD11BDAu;
  x0 += k0; x1 += k1;
#define TF_R(r) { x0 += x1; x1 = rotl32(x1, r); x1 ^= x0; }
  TF_R(13) TF_R(15) TF_R(26) TF_R(6)
  x0 += k1;  x1 += ks2 + 1u;
  TF_R(17) TF_R(29) TF_R(16) TF_R(24)
  x0 += ks2; x1 += k0 + 2u;
  TF_R(13) TF_R(15) TF_R(26) TF_R(6)
  x0 += k0;  x1 += k1 + 3u;
  TF_R(17) TF_R(29) TF_R(16) TF_R(24)
  x0 += k1;  x1 += ks2 + 4u;
  TF_R(13) TF_R(15) TF_R(26) TF_R(6)
  x0 += ks2; x1 += k0 + 5u;
#undef TF_R
  o0 = x0; o1 = x1;
}

// threefry_partitionable: bits[i] = o0 ^ o1 of cipher(key, (0, i))
__device__ __forceinline__ u32 tf_bits(u32 k0, u32 k1, u32 i) {
  u32 o0, o1;
  threefry2x32(k0, k1, 0u, i, o0, o1);
  return o0 ^ o1;
}

// kb = cipher((0,42),(0,b)); round1 sub = cipher(kb,(0,1));
// round2 sub = cipher(cipher(kb,(0,0)),(0,1))
__device__ void batch_round_key(int b, int round, u32& rk0, u32& rk1) {
  u32 kb0, kb1;
  threefry2x32(0u, 42u, 0u, (u32)b, kb0, kb1);
  if (round == 1) { threefry2x32(kb0, kb1, 0u, 1u, rk0, rk1); return; }
  u32 c0, c1;
  threefry2x32(kb0, kb1, 0u, 0u, c0, c1);
  threefry2x32(c0, c1, 0u, 1u, rk0, rk1);
}

// Coarse bucket scatter with LDS staging: bins by k1>>24 into 1024-slot regions.
// rec layout staged: e(0..16) | label(17..18) | bin(19..26); global keeps bits 0..18.
__global__ __launch_bounds__(256) void scatterA_kernel(u32* __restrict__ cursor, u32* __restrict__ binned,
                                                       const int* __restrict__ posg, const int* __restrict__ negg,
                                                       const int* __restrict__ igng, int batch0) {
  __shared__ u32 sk[2];
  __shared__ u32 hist[NCOARSE];
  __shared__ u32 lstart[NCOARSE];
  __shared__ u32 gbase[NCOARSE];
  __shared__ u32 staged[CHUNK];
  __shared__ u32 stmp[NCOARSE];
  int g = blockIdx.y;
  int b = batch0 + g;
  int tid = threadIdx.x;
  if (tid == 0) { u32 k0, k1; batch_round_key(b, 1, k0, k1); sk[0] = k0; sk[1] = k1; }
  if (tid < NCOARSE) hist[tid] = 0;
  __syncthreads();
  u32 base = blockIdx.x * CHUNK;
  u32 recs[16], rr[16];
  const int* P = posg + (size_t)b * NN;
  const int* Q = negg + (size_t)b * NN;
  const int* I = igng + (size_t)b * NN;
#pragma unroll
  for (int j = 0; j < 16; j++) {
    u32 e = base + j * 256 + tid;
    int p = P[e] != 0, n = Q[e] != 0, ig = I[e] != 0;
    u32 label = ((p | n) && !ig) ? (p ? 1u : 2u) : 0u;
    u32 k1 = tf_bits(sk[0], sk[1], e);
    u32 bin = k1 >> 24;
    rr[j] = atomicAdd(&hist[bin], 1u);
    recs[j] = e | (label << 17) | (bin << 19);
  }
  __syncthreads();
  // exclusive scan of hist -> lstart (Hillis-Steele over 256 by 256 threads)
  if (tid < NCOARSE) stmp[tid] = hist[tid];
  __syncthreads();
  for (int off = 1; off < NCOARSE; off <<= 1) {
    u32 t = 0;
    if (tid < NCOARSE && tid >= off) t = stmp[tid - off];
    __syncthreads();
    if (tid < NCOARSE) stmp[tid] += t;
    __syncthreads();
  }
  if (tid < NCOARSE) lstart[tid] = stmp[tid] - hist[tid];
  __syncthreads();
#pragma unroll
  for (int j = 0; j < 16; j++) {
    u32 bin = recs[j] >> 19;
    staged[lstart[bin] + rr[j]] = recs[j];
  }
  if (tid < NCOARSE) {
    u32 c = hist[tid];
    gbase[tid] = c ? atomicAdd(&cursor[(size_t)g * NCOARSE + tid], c) : 0u;
  }
  __syncthreads();
  u32* bn = binned + (size_t)g * NCOARSE * SLOT;
  for (int s = tid; s < CHUNK; s += 256) {
    u32 v = staged[s];
    u32 bin = v >> 19;
    u32 dst = bin * SLOT + gbase[bin] + ((u32)s - lstart[bin]);
    bn[dst] = v & 0x7FFFFu;  // e | label<<17
  }
}

// exclusive scan of 256 bucket counts per batch -> starts
__global__ __launch_bounds__(256) void scanB_kernel(const u32* __restrict__ cursor, u32* __restrict__ starts) {
  __shared__ u32 stmp[NCOARSE];
  __shared__ u32 cnts[NCOARSE];
  int g = blockIdx.x, tid = threadIdx.x;
  u32 v = cursor[(size_t)g * NCOARSE + tid];
  cnts[tid] = v; stmp[tid] = v;
  __syncthreads();
  for (int off = 1; off < NCOARSE; off <<= 1) {
    u32 t = (tid >= off) ? stmp[tid - off] : 0u;
    __syncthreads();
    stmp[tid] += t;
    __syncthreads();
  }
  starts[(size_t)g * NCOARSE + tid] = stmp[tid] - cnts[tid];
}

// One block sorts 8 buckets exactly (bitonic-1024 in LDS over (k1,e)), writes
// EL[p1] coalesced, accumulates pos/neg k2 histograms in LDS, merges once.
__global__ __launch_bounds__(512) void passB_kernel(const u32* __restrict__ cursor, const u32* __restrict__ starts,
                                                    const u32* __restrict__ binned, u32* __restrict__ EL,
                                                    u32* __restrict__ posh, u32* __restrict__ negh, int batch0) {
  __shared__ u32 sk1[2], sk2[2];
  __shared__ u64 keys[SLOT];
  __shared__ u32 lpos[NCOARSE], lneg[NCOARSE];
  int g = blockIdx.y;
  int tid = threadIdx.x;
  if (tid == 0) {
    u32 a, c;
    batch_round_key(batch0 + g, 1, a, c); sk1[0] = a; sk1[1] = c;
    batch_round_key(batch0 + g, 2, a, c); sk2[0] = a; sk2[1] = c;
  }
  if (tid < NCOARSE) { lpos[tid] = 0; lneg[tid] = 0; }
  __syncthreads();
  const u32* bn = binned + (size_t)g * NCOARSE * SLOT;
  u32* el = EL + (size_t)g * NN;
  for (int q = 0; q < 8; q++) {
    u32 bin = blockIdx.x * 8 + q;
    u32 cnt = cursor[(size_t)g * NCOARSE + bin];
    if (cnt > SLOT) cnt = SLOT;
    u32 start = starts[(size_t)g * NCOARSE + bin];
#pragma unroll
    for (int i = tid; i < SLOT; i += 512) {
      if (i < (int)cnt) {
        u32 v = bn[bin * SLOT + i];
        u32 e = v & EMASK17;
        u32 k1 = tf_bits(sk1[0], sk1[1], e);
        keys[i] = ((u64)k1 << 19) | ((u64)v << 2 & 0x7FFFCull) | (u64)(v >> 17);
        // bits: k1 [19..50], e [2..18], label [0..1]  (tie-break by e; e unique)
      } else {
        keys[i] = ~0ull;
      }
    }
    __syncthreads();
    for (int k = 2; k <= SLOT; k <<= 1) {
      for (int j = k >> 1; j > 0; j >>= 1) {
#pragma unroll
        for (int i = tid; i < SLOT; i += 512) {
          int l = i ^ j;
          if (l > i) {
            u64 a = keys[i], c = keys[l];
            bool up = ((i & k) == 0);
            if ((a > c) == up) { keys[i] = c; keys[l] = a; }
          }
        }
        __syncthreads();
      }
    }
#pragma unroll
    for (int i = tid; i < (int)cnt; i += 512) {
      u64 key = keys[i];
      u32 e = (u32)(key >> 2) & EMASK17;
      u32 label = (u32)key & 3u;
      u32 p1 = start + (u32)i;
      el[p1] = e | (label << 17);
      if (label) {
        u32 k2 = tf_bits(sk2[0], sk2[1], p1);
        if (label == 1) atomicAdd(&lpos[k2 >> 24], 1u);
        else atomicAdd(&lneg[k2 >> 24], 1u);
      }
    }
    __syncthreads();
  }
  if (tid < NCOARSE) {
    if (lpos[tid]) atomicAdd(&posh[(size_t)g * NCOARSE + tid], lpos[tid]);
    if (lneg[tid]) atomicAdd(&negh[(size_t)g * NCOARSE + tid], lneg[tid]);
  }
}

// Per batch: qp = min(128,np), qn = 512-qp; threshold bins over 256-bin hists.
__global__ __launch_bounds__(256) void threshold_kernel(const u32* __restrict__ posh,
                                                        const u32* __restrict__ negh,
                                                        u32* __restrict__ params) {
  int g = blockIdx.x, tid = threadIdx.x;
  __shared__ u32 rp[NCOARSE], rn[NCOARSE];
  rp[tid] = posh[(size_t)g * NCOARSE + tid];
  rn[tid] = negh[(size_t)g * NCOARSE + tid];
  __syncthreads();
  if (tid == 0) {
    u32 np = 0;
    for (int i = 0; i < NCOARSE; i++) np += rp[i];
    u32 qp = np < 128 ? np : 128;
    u32 qn = 512 - qp;
    u32 tp = 256;
    if (qp > 0) {
      u32 cum = 0;
      for (int i = 255; i >= 0; i--) { cum += rp[i]; if (cum >= qp) { tp = (u32)i; break; } }
    }
    u32 tn = 0, cum = 0;
    for (int i = 255; i >= 0; i--) { cum += rn[i]; if (cum >= qn) { tn = (u32)i; break; } }
    u32* pr = params + (size_t)g * 4;
    pr[0] = tp; pr[1] = tn; pr[2] = qp; pr[3] = qn;
  }
}

// Coalesced pass over EL: recompute k2 from p1, collect threshold survivors.
__global__ void collect_kernel(const u32* __restrict__ EL, const u32* __restrict__ params,
                               u32* __restrict__ cnt, u64* __restrict__ poskey, u32* __restrict__ posval,
                               u64* __restrict__ negkey, u32* __restrict__ negval, int batch0) {
  __shared__ u32 sk[2];
  __shared__ u32 sp[2];
  int g = blockIdx.y;
  if (threadIdx.x == 0) {
    u32 k0, k1; batch_round_key(batch0 + g, 2, k0, k1); sk[0] = k0; sk[1] = k1;
    const u32* pr = params + (size_t)g * 4; sp[0] = pr[0]; sp[1] = pr[1];
  }
  __syncthreads();
  u32 p1 = blockIdx.x * blockDim.x + threadIdx.x;
  u32 val = EL[(size_t)g * NN + p1];
  u32 label = val >> 17;
  if (!label) return;
  u32 k2 = tf_bits(sk[0], sk[1], p1);
  if (label == 1) {
    if ((k2 >> 24) >= sp[0]) {
      u32 s = atomicAdd(&cnt[(size_t)g * 2], 1u);
      if (s < CAP) { poskey[(size_t)g * CAP + s] = ((u64)k2 << 32) | p1; posval[(size_t)g * CAP + s] = val; }
    }
  } else {
    if ((k2 >> 24) >= sp[1]) {
      u32 s = atomicAdd(&cnt[(size_t)g * 2 + 1], 1u);
      if (s < CAP) { negkey[(size_t)g * CAP + s] = ((u64)k2 << 32) | p1; negval[(size_t)g * CAP + s] = val; }
    }
  }
}

// Per batch: exact top-qp / top-qn by (k2,p1) desc over collected, then 512
// ascending index sort -> output.
__global__ __launch_bounds__(1024) void select_final_kernel(const u32* __restrict__ params,
                                                            const u32* __restrict__ cnt,
                                                            const u64* __restrict__ poskey,
                                                            const u32* __restrict__ posval,
                                                            const u64* __restrict__ negkey,
                                                            const u32* __restrict__ negval,
                                                            int* __restrict__ out, int batch0) {
  int g = blockIdx.x, tid = threadIdx.x, b = batch0 + g;
  __shared__ u64 skey[1024];
  __shared__ u32 sval[1024];
  __shared__ int sel[512];
  const u32* pr = params + (size_t)g * 4;
  u32 qp = pr[2], qn = pr[3];
  u32 cp = cnt[(size_t)g * 2]; if (cp > CAP) cp = CAP;
  u32 cn = cnt[(size_t)g * 2 + 1]; if (cn > CAP) cn = CAP;
  if (tid < 512) sel[tid] = 0;

  skey[tid] = (tid < (int)cp) ? poskey[(size_t)g * CAP + tid] : 0ull;
  sval[tid] = (tid < (int)cp) ? posval[(size_t)g * CAP + tid] : 0u;
  __syncthreads();
  for (int k = 2; k <= 1024; k <<= 1)
    for (int s = k >> 1; s > 0; s >>= 1) {
      if (tid < 512) {
        int i = ((tid & ~(s - 1)) << 1) | (tid & (s - 1));
        int j = i | s;
        bool up = ((i & k) == 0);
        if ((skey[i] < skey[j]) == up) {
          u64 tk = skey[i]; skey[i] = skey[j]; skey[j] = tk;
          u32 tv = sval[i]; sval[i] = sval[j]; sval[j] = tv;
        }
      }
      __syncthreads();
    }
  if (tid < (int)qp) sel[tid] = (int)(sval[tid] & EMASK17);
  __syncthreads();

  skey[tid] = (tid < (int)cn) ? negkey[(size_t)g * CAP + tid] : 0ull;
  sval[tid] = (tid < (int)cn) ? negval[(size_t)g * CAP + tid] : 0u;
  __syncthreads();
  for (int k = 2; k <= 1024; k <<= 1)
    for (int s = k >> 1; s > 0; s >>= 1) {
      if (tid < 512) {
        int i = ((tid & ~(s - 1)) << 1) | (tid & (s - 1));
        int j = i | s;
        bool up = ((i & k) == 0);
        if ((skey[i] < skey[j]) == up) {
          u64 tk = skey[i]; skey[i] = skey[j]; skey[j] = tk;
          u32 tv = sval[i]; sval[i] = sval[j]; sval[j] = tv;
        }
      }
      __syncthreads();
    }
  if (tid < (int)qn) sel[qp + tid] = (int)(sval[tid] & EMASK17);
  __syncthreads();

  for (int k = 2; k <= 512; k <<= 1)
    for (int s = k >> 1; s > 0; s >>= 1) {
      if (tid < 256) {
        int i = ((tid & ~(s - 1)) << 1) | (tid & (s - 1));
        int j = i | s;
        bool up = ((i & k) == 0);
        int a = sel[i], c = sel[j];
        if ((a > c) == up) { sel[i] = c; sel[j] = a; }
      }
      __syncthreads();
    }
  if (tid < 512) out[(size_t)b * 512 + tid] = sel[tid];
}

extern "C" void kernel_launch(void* const* d_in, const int* in_sizes, int n_in,
                              void* d_out, int out_size, void* d_ws, size_t ws_size,
                              hipStream_t stream) {
  const int* pos = (const int*)d_in[0];
  const int* neg = (const int*)d_in[1];
  const int* ign = (const int*)d_in[2];
  int* out = (int*)d_out;

  // per-batch ws: zero-region (cursor 1KB + posh 1KB + negh 1KB + cnt 8B)
  //             + binned 1MB + EL 512KB + starts 1KB + params 16B + CAP arrays 24KB
  size_t zeroPer = (NCOARSE * 3 + 2) * 4;
  size_t perBatch = zeroPer + (size_t)NCOARSE * SLOT * 4 + (size_t)NN * 4 + NCOARSE * 4 + 16 +
                    (size_t)CAP * (8 + 8 + 4 + 4);
  int G = (int)(ws_size / perBatch);
  if (G > BATCH) G = BATCH;
  if (G < 1) G = 1;

  char* p = (char*)d_ws;
  u32* cursor = (u32*)p;            p += (size_t)G * NCOARSE * 4;
  u32* posh = (u32*)p;              p += (size_t)G * NCOARSE * 4;
  u32* negh = (u32*)p;              p += (size_t)G * NCOARSE * 4;
  u32* cnt = (u32*)p;               p += (size_t)G * 2 * 4;
  size_t zeroBytes = (size_t)p - (size_t)d_ws;
  u32* binned = (u32*)p;            p += (size_t)G * NCOARSE * SLOT * 4;
  u32* EL = (u32*)p;                p += (size_t)G * NN * 4;
  u32* starts = (u32*)p;            p += (size_t)G * NCOARSE * 4;
  u32* params = (u32*)p;            p += (size_t)G * 4 * 4;
  u64* poskey = (u64*)p;            p += (size_t)G * CAP * 8;
  u64* negkey = (u64*)p;            p += (size_t)G * CAP * 8;
  u32* posval = (u32*)p;            p += (size_t)G * CAP * 4;
  u32* negval = (u32*)p;            p += (size_t)G * CAP * 4;

  for (int batch0 = 0; batch0 < BATCH; batch0 += G) {
    int Gi = (BATCH - batch0 < G) ? (BATCH - batch0) : G;
    hipMemsetAsync(d_ws, 0, zeroBytes, stream);
    dim3 gridS(NN / CHUNK, Gi);
    scatterA_kernel<<<gridS, 256, 0, stream>>>(cursor, binned, pos, neg, ign, batch0);
    scanB_kernel<<<Gi, 256, 0, stream>>>(cursor, starts);
    dim3 gridP(NCOARSE / 8, Gi);
    passB_kernel<<<gridP, 512, 0, stream>>>(cursor, starts, binned, EL, posh, negh, batch0);
    threshold_kernel<<<Gi, 256, 0, stream>>>(posh, negh, params);
    dim3 gridC(NN / 256, Gi);
    collect_kernel<<<gridC, 256, 0, stream>>>(EL, params, cnt, poskey, posval, negkey, negval, batch0);
    select_final_kernel<<<Gi, 1024, 0, stream>>>(params, cnt, poskey, posval, negkey, negval, out, batch0);
  }
}

// Round 5
// 722.901 us; speedup vs baseline: 3.8561x; 1.3612x over previous
//
#include <hip/hip_runtime.h>
#include <stdint.h>

#define BATCH 64
#define NN 131072
#define NCOARSE 256
#define SLOT 1024
#define CHUNK 4096
#define NSUB 512
#define EMASK17 0x1FFFFu
#define CAP 1024

typedef uint32_t u32;
typedef uint64_t u64;

__device__ __forceinline__ u32 rotl32(u32 v, int d) { return (v << d) | (v >> (32 - d)); }

// Exact port of JAX threefry2x32 block cipher
__device__ __forceinline__ void threefry2x32(u32 k0, u32 k1, u32 x0, u32 x1, u32& o0, u32& o1) {
  u32 ks2 = k0 ^ k1 ^ 0x1BD11BDAu;
  x0 += k0; x1 += k1;
#define TF_R(r) { x0 += x1; x1 = rotl32(x1, r); x1 ^= x0; }
  TF_R(13) TF_R(15) TF_R(26) TF_R(6)
  x0 += k1;  x1 += ks2 + 1u;
  TF_R(17) TF_R(29) TF_R(16) TF_R(24)
  x0 += ks2; x1 += k0 + 2u;
  TF_R(13) TF_R(15) TF_R(26) TF_R(6)
  x0 += k0;  x1 += k1 + 3u;
  TF_R(17) TF_R(29) TF_R(16) TF_R(24)
  x0 += k1;  x1 += ks2 + 4u;
  TF_R(13) TF_R(15) TF_R(26) TF_R(6)
  x0 += ks2; x1 += k0 + 5u;
#undef TF_R
  o0 = x0; o1 = x1;
}

// threefry_partitionable: bits[i] = o0 ^ o1 of cipher(key, (0, i))
__device__ __forceinline__ u32 tf_bits(u32 k0, u32 k1, u32 i) {
  u32 o0, o1;
  threefry2x32(k0, k1, 0u, i, o0, o1);
  return o0 ^ o1;
}

// kb = cipher((0,42),(0,b)); round1 sub = cipher(kb,(0,1));
// round2 sub = cipher(cipher(kb,(0,0)),(0,1))
__device__ void batch_round_key(int b, int round, u32& rk0, u32& rk1) {
  u32 kb0, kb1;
  threefry2x32(0u, 42u, 0u, (u32)b, kb0, kb1);
  if (round == 1) { threefry2x32(kb0, kb1, 0u, 1u, rk0, rk1); return; }
  u32 c0, c1;
  threefry2x32(kb0, kb1, 0u, 0u, c0, c1);
  threefry2x32(c0, c1, 0u, 1u, rk0, rk1);
}

// Coarse bucket scatter with LDS staging: bins by k1>>24 into 1024-slot regions.
// rec layout staged: e(0..16) | label(17..18) | bin(19..26); global keeps bits 0..18.
// Within-bucket staging order is irrelevant: passB does an exact stable re-sort.
__global__ __launch_bounds__(256) void scatterA_kernel(u32* __restrict__ cursor, u32* __restrict__ binned,
                                                       const int* __restrict__ posg, const int* __restrict__ negg,
                                                       const int* __restrict__ igng, int batch0) {
  __shared__ u32 sk[2];
  __shared__ u32 hist[NCOARSE];
  __shared__ u32 lstart[NCOARSE];
  __shared__ u32 gbase[NCOARSE];
  __shared__ u32 staged[CHUNK];
  __shared__ u32 stmp[NCOARSE];
  int g = blockIdx.y;
  int b = batch0 + g;
  int tid = threadIdx.x;
  if (tid == 0) { u32 k0, k1; batch_round_key(b, 1, k0, k1); sk[0] = k0; sk[1] = k1; }
  if (tid < NCOARSE) hist[tid] = 0;
  __syncthreads();
  u32 base = blockIdx.x * CHUNK;
  u32 recs[16], rr[16];
  const int4* P4 = (const int4*)(posg + (size_t)b * NN);
  const int4* Q4 = (const int4*)(negg + (size_t)b * NN);
  const int4* I4 = (const int4*)(igng + (size_t)b * NN);
#pragma unroll
  for (int j = 0; j < 4; j++) {
    u32 e0 = base + j * 1024 + tid * 4;
    int4 pv = P4[e0 >> 2];
    int4 nv = Q4[e0 >> 2];
    int4 iv = I4[e0 >> 2];
#pragma unroll
    for (int m = 0; m < 4; m++) {
      u32 e = e0 + m;
      int p = (&pv.x)[m] != 0, n = (&nv.x)[m] != 0, ig = (&iv.x)[m] != 0;
      u32 label = ((p | n) && !ig) ? (p ? 1u : 2u) : 0u;
      u32 k1 = tf_bits(sk[0], sk[1], e);
      u32 bin = k1 >> 24;
      rr[j * 4 + m] = atomicAdd(&hist[bin], 1u);
      recs[j * 4 + m] = e | (label << 17) | (bin << 19);
    }
  }
  __syncthreads();
  if (tid < NCOARSE) stmp[tid] = hist[tid];
  __syncthreads();
  for (int off = 1; off < NCOARSE; off <<= 1) {
    u32 t = 0;
    if (tid < NCOARSE && tid >= off) t = stmp[tid - off];
    __syncthreads();
    if (tid < NCOARSE) stmp[tid] += t;
    __syncthreads();
  }
  if (tid < NCOARSE) lstart[tid] = stmp[tid] - hist[tid];
  __syncthreads();
#pragma unroll
  for (int j = 0; j < 16; j++) {
    u32 bin = recs[j] >> 19;
    staged[lstart[bin] + rr[j]] = recs[j];
  }
  if (tid < NCOARSE) {
    u32 c = hist[tid];
    gbase[tid] = c ? atomicAdd(&cursor[(size_t)g * NCOARSE + tid], c) : 0u;
  }
  __syncthreads();
  u32* bn = binned + (size_t)g * NCOARSE * SLOT;
  for (int s = tid; s < CHUNK; s += 256) {
    u32 v = staged[s];
    u32 bin = v >> 19;
    u32 dst = bin * SLOT + gbase[bin] + ((u32)s - lstart[bin]);
    bn[dst] = v & 0x7FFFFu;  // e | label<<17
  }
}

// exclusive scan of 256 bucket counts per batch -> starts
__global__ __launch_bounds__(256) void scanB_kernel(const u32* __restrict__ cursor, u32* __restrict__ starts) {
  __shared__ u32 stmp[NCOARSE];
  __shared__ u32 cnts[NCOARSE];
  int g = blockIdx.x, tid = threadIdx.x;
  u32 v = cursor[(size_t)g * NCOARSE + tid];
  cnts[tid] = v; stmp[tid] = v;
  __syncthreads();
  for (int off = 1; off < NCOARSE; off <<= 1) {
    u32 t = (tid >= off) ? stmp[tid - off] : 0u;
    __syncthreads();
    stmp[tid] += t;
    __syncthreads();
  }
  starts[(size_t)g * NCOARSE + tid] = stmp[tid] - cnts[tid];
}

// One block handles 8 buckets. Per bucket: counting sub-sort instead of bitonic —
// sub-bin by k1 bits 23..15 (512 LDS sub-bins, Poisson(1)), hist -> scan ->
// scatter -> per-thread exact stable rank of its own sub-bin by full (k1,e).
// position-in-bucket = subbin_excl_start + rank (sub-bin index is a key prefix).
__global__ __launch_bounds__(512) void passB_kernel(const u32* __restrict__ cursor, const u32* __restrict__ starts,
                                                    const u32* __restrict__ binned, u32* __restrict__ EL,
                                                    u32* __restrict__ posh, u32* __restrict__ negh, int batch0) {
  __shared__ u32 sk1[2], sk2[2];
  __shared__ u64 keys[SLOT];
  __shared__ u32 hist[NSUB];
  __shared__ u32 sstart[NSUB];
  __shared__ u32 lpos[NCOARSE], lneg[NCOARSE];
  int g = blockIdx.y;
  int tid = threadIdx.x;
  if (tid == 0) {
    u32 a, c;
    batch_round_key(batch0 + g, 1, a, c); sk1[0] = a; sk1[1] = c;
    batch_round_key(batch0 + g, 2, a, c); sk2[0] = a; sk2[1] = c;
  }
  if (tid < NCOARSE) { lpos[tid] = 0; lneg[tid] = 0; }
  __syncthreads();
  const u32* bn = binned + (size_t)g * NCOARSE * SLOT;
  u32* el = EL + (size_t)g * NN;
  for (int q = 0; q < 8; q++) {
    u32 bin = blockIdx.x * 8 + q;
    u32 cnt = cursor[(size_t)g * NCOARSE + bin];
    if (cnt > SLOT) cnt = SLOT;
    u32 start = starts[(size_t)g * NCOARSE + bin];
    hist[tid] = 0;
    __syncthreads();
    // load + sub-bin histogram; keep key/sub/rank-ticket in registers
    u64 mykey[2]; u32 mysr[2];
#pragma unroll
    for (int t = 0; t < 2; t++) {
      int i = tid + t * 512;
      if (i < (int)cnt) {
        u32 v = bn[bin * SLOT + i];
        u32 e = v & EMASK17;
        u32 k1 = tf_bits(sk1[0], sk1[1], e);
        mykey[t] = ((u64)k1 << 19) | ((u64)e << 2) | (u64)(v >> 17);  // k1 | e | label
        u32 sub = (k1 >> 15) & 0x1FFu;
        u32 r = atomicAdd(&hist[sub], 1u);
        mysr[t] = (sub << 9) | r;  // r < 512 always (occupancy ~1)
      } else {
        mysr[t] = 0xFFFFFFFFu;
      }
    }
    __syncthreads();
    // exclusive scan of hist over 512 sub-bins
    u32 h = hist[tid];
    sstart[tid] = h;
    __syncthreads();
    for (int off = 1; off < NSUB; off <<= 1) {
      u32 t2 = (tid >= off) ? sstart[tid - off] : 0u;
      __syncthreads();
      sstart[tid] += t2;
      __syncthreads();
    }
    u32 myexcl = sstart[tid] - h;
    __syncthreads();
    sstart[tid] = myexcl;
    __syncthreads();
    // scatter into sub-bin-grouped order
#pragma unroll
    for (int t = 0; t < 2; t++) {
      if (mysr[t] != 0xFFFFFFFFu)
        keys[sstart[mysr[t] >> 9] + (mysr[t] & 0x1FFu)] = mykey[t];
    }
    __syncthreads();
    // exact stable rank of own sub-bin (compare full (k1,e); e unique)
    for (u32 i = 0; i < h; i++) {
      u64 ki = keys[myexcl + i];
      u32 r = 0;
      for (u32 j = 0; j < h; j++) {
        if (j != i && keys[myexcl + j] < ki) r++;
      }
      u32 p1 = start + myexcl + r;
      u32 e = (u32)(ki >> 2) & EMASK17;
      u32 label = (u32)ki & 3u;
      el[p1] = e | (label << 17);
      if (label) {
        u32 k2 = tf_bits(sk2[0], sk2[1], p1);
        if (label == 1) atomicAdd(&lpos[k2 >> 24], 1u);
        else atomicAdd(&lneg[k2 >> 24], 1u);
      }
    }
    __syncthreads();
  }
  if (tid < NCOARSE) {
    if (lpos[tid]) atomicAdd(&posh[(size_t)g * NCOARSE + tid], lpos[tid]);
  } else {
    int t = tid - NCOARSE;
    if (lneg[t]) atomicAdd(&negh[(size_t)g * NCOARSE + t], lneg[t]);
  }
}

// Per batch: qp = min(128,np), qn = 512-qp; threshold bins over 256-bin hists.
__global__ __launch_bounds__(256) void threshold_kernel(const u32* __restrict__ posh,
                                                        const u32* __restrict__ negh,
                                                        u32* __restrict__ params) {
  int g = blockIdx.x, tid = threadIdx.x;
  __shared__ u32 rp[NCOARSE], rn[NCOARSE];
  rp[tid] = posh[(size_t)g * NCOARSE + tid];
  rn[tid] = negh[(size_t)g * NCOARSE + tid];
  __syncthreads();
  if (tid == 0) {
    u32 np = 0;
    for (int i = 0; i < NCOARSE; i++) np += rp[i];
    u32 qp = np < 128 ? np : 128;
    u32 qn = 512 - qp;
    u32 tp = 256;
    if (qp > 0) {
      u32 cum = 0;
      for (int i = 255; i >= 0; i--) { cum += rp[i]; if (cum >= qp) { tp = (u32)i; break; } }
    }
    u32 tn = 0, cum = 0;
    for (int i = 255; i >= 0; i--) { cum += rn[i]; if (cum >= qn) { tn = (u32)i; break; } }
    u32* pr = params + (size_t)g * 4;
    pr[0] = tp; pr[1] = tn; pr[2] = qp; pr[3] = qn;
  }
}

// Coalesced pass over EL: recompute k2 from p1, collect threshold survivors.
__global__ void collect_kernel(const u32* __restrict__ EL, const u32* __restrict__ params,
                               u32* __restrict__ cnt, u64* __restrict__ poskey, u32* __restrict__ posval,
                               u64* __restrict__ negkey, u32* __restrict__ negval, int batch0) {
  __shared__ u32 sk[2];
  __shared__ u32 sp[2];
  int g = blockIdx.y;
  if (threadIdx.x == 0) {
    u32 k0, k1; batch_round_key(batch0 + g, 2, k0, k1); sk[0] = k0; sk[1] = k1;
    const u32* pr = params + (size_t)g * 4; sp[0] = pr[0]; sp[1] = pr[1];
  }
  __syncthreads();
  u32 p1 = blockIdx.x * blockDim.x + threadIdx.x;
  u32 val = EL[(size_t)g * NN + p1];
  u32 label = val >> 17;
  if (!label) return;
  u32 k2 = tf_bits(sk[0], sk[1], p1);
  if (label == 1) {
    if ((k2 >> 24) >= sp[0]) {
      u32 s = atomicAdd(&cnt[(size_t)g * 2], 1u);
      if (s < CAP) { poskey[(size_t)g * CAP + s] = ((u64)k2 << 32) | p1; posval[(size_t)g * CAP + s] = val; }
    }
  } else {
    if ((k2 >> 24) >= sp[1]) {
      u32 s = atomicAdd(&cnt[(size_t)g * 2 + 1], 1u);
      if (s < CAP) { negkey[(size_t)g * CAP + s] = ((u64)k2 << 32) | p1; negval[(size_t)g * CAP + s] = val; }
    }
  }
}

// Per batch: exact top-qp / top-qn by (k2,p1) desc over collected, then 512
// ascending index sort -> output.
__global__ __launch_bounds__(1024) void select_final_kernel(const u32* __restrict__ params,
                                                            const u32* __restrict__ cnt,
                                                            const u64* __restrict__ poskey,
                                                            const u32* __restrict__ posval,
                                                            const u64* __restrict__ negkey,
                                                            const u32* __restrict__ negval,
                                                            int* __restrict__ out, int batch0) {
  int g = blockIdx.x, tid = threadIdx.x, b = batch0 + g;
  __shared__ u64 skey[1024];
  __shared__ u32 sval[1024];
  __shared__ int sel[512];
  const u32* pr = params + (size_t)g * 4;
  u32 qp = pr[2], qn = pr[3];
  u32 cp = cnt[(size_t)g * 2]; if (cp > CAP) cp = CAP;
  u32 cn = cnt[(size_t)g * 2 + 1]; if (cn > CAP) cn = CAP;
  if (tid < 512) sel[tid] = 0;

  skey[tid] = (tid < (int)cp) ? poskey[(size_t)g * CAP + tid] : 0ull;
  sval[tid] = (tid < (int)cp) ? posval[(size_t)g * CAP + tid] : 0u;
  __syncthreads();
  for (int k = 2; k <= 1024; k <<= 1)
    for (int s = k >> 1; s > 0; s >>= 1) {
      if (tid < 512) {
        int i = ((tid & ~(s - 1)) << 1) | (tid & (s - 1));
        int j = i | s;
        bool up = ((i & k) == 0);
        if ((skey[i] < skey[j]) == up) {
          u64 tk = skey[i]; skey[i] = skey[j]; skey[j] = tk;
          u32 tv = sval[i]; sval[i] = sval[j]; sval[j] = tv;
        }
      }
      __syncthreads();
    }
  if (tid < (int)qp) sel[tid] = (int)(sval[tid] & EMASK17);
  __syncthreads();

  skey[tid] = (tid < (int)cn) ? negkey[(size_t)g * CAP + tid] : 0ull;
  sval[tid] = (tid < (int)cn) ? negval[(size_t)g * CAP + tid] : 0u;
  __syncthreads();
  for (int k = 2; k <= 1024; k <<= 1)
    for (int s = k >> 1; s > 0; s >>= 1) {
      if (tid < 512) {
        int i = ((tid & ~(s - 1)) << 1) | (tid & (s - 1));
        int j = i | s;
        bool up = ((i & k) == 0);
        if ((skey[i] < skey[j]) == up) {
          u64 tk = skey[i]; skey[i] = skey[j]; skey[j] = tk;
          u32 tv = sval[i]; sval[i] = sval[j]; sval[j] = tv;
        }
      }
      __syncthreads();
    }
  if (tid < (int)qn) sel[qp + tid] = (int)(sval[tid] & EMASK17);
  __syncthreads();

  for (int k = 2; k <= 512; k <<= 1)
    for (int s = k >> 1; s > 0; s >>= 1) {
      if (tid < 256) {
        int i = ((tid & ~(s - 1)) << 1) | (tid & (s - 1));
        int j = i | s;
        bool up = ((i & k) == 0);
        int a = sel[i], c = sel[j];
        if ((a > c) == up) { sel[i] = c; sel[j] = a; }
      }
      __syncthreads();
    }
  if (tid < 512) out[(size_t)b * 512 + tid] = sel[tid];
}

extern "C" void kernel_launch(void* const* d_in, const int* in_sizes, int n_in,
                              void* d_out, int out_size, void* d_ws, size_t ws_size,
                              hipStream_t stream) {
  const int* pos = (const int*)d_in[0];
  const int* neg = (const int*)d_in[1];
  const int* ign = (const int*)d_in[2];
  int* out = (int*)d_out;

  // per-batch ws: zero-region (cursor 1KB + posh 1KB + negh 1KB + cnt 8B)
  //             + binned 1MB + EL 512KB + starts 1KB + params 16B + CAP arrays 24KB
  size_t zeroPer = (NCOARSE * 3 + 2) * 4;
  size_t perBatch = zeroPer + (size_t)NCOARSE * SLOT * 4 + (size_t)NN * 4 + NCOARSE * 4 + 16 +
                    (size_t)CAP * (8 + 8 + 4 + 4);
  int G = (int)(ws_size / perBatch);
  if (G > BATCH) G = BATCH;
  if (G < 1) G = 1;

  char* p = (char*)d_ws;
  u32* cursor = (u32*)p;            p += (size_t)G * NCOARSE * 4;
  u32* posh = (u32*)p;              p += (size_t)G * NCOARSE * 4;
  u32* negh = (u32*)p;              p += (size_t)G * NCOARSE * 4;
  u32* cnt = (u32*)p;               p += (size_t)G * 2 * 4;
  size_t zeroBytes = (size_t)p - (size_t)d_ws;
  u32* binned = (u32*)p;            p += (size_t)G * NCOARSE * SLOT * 4;
  u32* EL = (u32*)p;                p += (size_t)G * NN * 4;
  u32* starts = (u32*)p;            p += (size_t)G * NCOARSE * 4;
  u32* params = (u32*)p;            p += (size_t)G * 4 * 4;
  u64* poskey = (u64*)p;            p += (size_t)G * CAP * 8;
  u64* negkey = (u64*)p;            p += (size_t)G * CAP * 8;
  u32* posval = (u32*)p;            p += (size_t)G * CAP * 4;
  u32* negval = (u32*)p;            p += (size_t)G * CAP * 4;

  for (int batch0 = 0; batch0 < BATCH; batch0 += G) {
    int Gi = (BATCH - batch0 < G) ? (BATCH - batch0) : G;
    hipMemsetAsync(d_ws, 0, zeroBytes, stream);
    dim3 gridS(NN / CHUNK, Gi);
    scatterA_kernel<<<gridS, 256, 0, stream>>>(cursor, binned, pos, neg, ign, batch0);
    scanB_kernel<<<Gi, 256, 0, stream>>>(cursor, starts);
    dim3 gridP(NCOARSE / 8, Gi);
    passB_kernel<<<gridP, 512, 0, stream>>>(cursor, starts, binned, EL, posh, negh, batch0);
    threshold_kernel<<<Gi, 256, 0, stream>>>(posh, negh, params);
    dim3 gridC(NN / 256, Gi);
    collect_kernel<<<gridC, 256, 0, stream>>>(EL, params, cnt, poskey, posval, negkey, negval, batch0);
    select_final_kernel<<<Gi, 1024, 0, stream>>>(params, cnt, poskey, posval, negkey, negval, out, batch0);
  }
}

// Round 6
// 469.636 us; speedup vs baseline: 5.9356x; 1.5393x over previous
//
#include <hip/hip_runtime.h>
#include <stdint.h>

#define BATCH 64
#define NN 131072
#define NCOARSE 256
#define SLOT 1024
#define CHUNK 4096
#define NSUB 512
#define EMASK17 0x1FFFFu
#define CAP 1024

typedef uint32_t u32;
typedef uint64_t u64;

__device__ __forceinline__ u32 rotl32(u32 v, int d) { return (v << d) | (v >> (32 - d)); }

// Exact port of JAX threefry2x32 block cipher
__device__ __forceinline__ void threefry2x32(u32 k0, u32 k1, u32 x0, u32 x1, u32& o0, u32& o1) {
  u32 ks2 = k0 ^ k1 ^ 0x1BD11BDAu;
  x0 += k0; x1 += k1;
#define TF_R(r) { x0 += x1; x1 = rotl32(x1, r); x1 ^= x0; }
  TF_R(13) TF_R(15) TF_R(26) TF_R(6)
  x0 += k1;  x1 += ks2 + 1u;
  TF_R(17) TF_R(29) TF_R(16) TF_R(24)
  x0 += ks2; x1 += k0 + 2u;
  TF_R(13) TF_R(15) TF_R(26) TF_R(6)
  x0 += k0;  x1 += k1 + 3u;
  TF_R(17) TF_R(29) TF_R(16) TF_R(24)
  x0 += k1;  x1 += ks2 + 4u;
  TF_R(13) TF_R(15) TF_R(26) TF_R(6)
  x0 += ks2; x1 += k0 + 5u;
#undef TF_R
  o0 = x0; o1 = x1;
}

// threefry_partitionable: bits[i] = o0 ^ o1 of cipher(key, (0, i))
__device__ __forceinline__ u32 tf_bits(u32 k0, u32 k1, u32 i) {
  u32 o0, o1;
  threefry2x32(k0, k1, 0u, i, o0, o1);
  return o0 ^ o1;
}

// kb = cipher((0,42),(0,b)); round1 sub = cipher(kb,(0,1));
// round2 sub = cipher(cipher(kb,(0,0)),(0,1))
__device__ void batch_round_key(int b, int round, u32& rk0, u32& rk1) {
  u32 kb0, kb1;
  threefry2x32(0u, 42u, 0u, (u32)b, kb0, kb1);
  if (round == 1) { threefry2x32(kb0, kb1, 0u, 1u, rk0, rk1); return; }
  u32 c0, c1;
  threefry2x32(kb0, kb1, 0u, 0u, c0, c1);
  threefry2x32(c0, c1, 0u, 1u, rk0, rk1);
}

// Coarse bucket scatter with LDS staging: bins by k1>>24 into 1024-slot regions.
// rec layout staged: e(0..16) | label(17..18) | bin(19..26); global keeps bits 0..18.
// Within-bucket staging order is irrelevant: passB does an exact stable re-sort.
__global__ __launch_bounds__(256) void scatterA_kernel(u32* __restrict__ cursor, u32* __restrict__ binned,
                                                       const int* __restrict__ posg, const int* __restrict__ negg,
                                                       const int* __restrict__ igng, int batch0) {
  __shared__ u32 sk[2];
  __shared__ u32 hist[NCOARSE];
  __shared__ u32 lstart[NCOARSE];
  __shared__ u32 gbase[NCOARSE];
  __shared__ u32 staged[CHUNK];
  __shared__ u32 stmp[NCOARSE];
  int g = blockIdx.y;
  int b = batch0 + g;
  int tid = threadIdx.x;
  if (tid == 0) { u32 k0, k1; batch_round_key(b, 1, k0, k1); sk[0] = k0; sk[1] = k1; }
  if (tid < NCOARSE) hist[tid] = 0;
  __syncthreads();
  u32 base = blockIdx.x * CHUNK;
  u32 recs[16], rr[16];
  const int4* P4 = (const int4*)(posg + (size_t)b * NN);
  const int4* Q4 = (const int4*)(negg + (size_t)b * NN);
  const int4* I4 = (const int4*)(igng + (size_t)b * NN);
#pragma unroll
  for (int j = 0; j < 4; j++) {
    u32 e0 = base + j * 1024 + tid * 4;
    int4 pv = P4[e0 >> 2];
    int4 nv = Q4[e0 >> 2];
    int4 iv = I4[e0 >> 2];
#pragma unroll
    for (int m = 0; m < 4; m++) {
      u32 e = e0 + m;
      int p = (&pv.x)[m] != 0, n = (&nv.x)[m] != 0, ig = (&iv.x)[m] != 0;
      u32 label = ((p | n) && !ig) ? (p ? 1u : 2u) : 0u;
      u32 k1 = tf_bits(sk[0], sk[1], e);
      u32 bin = k1 >> 24;
      rr[j * 4 + m] = atomicAdd(&hist[bin], 1u);
      recs[j * 4 + m] = e | (label << 17) | (bin << 19);
    }
  }
  __syncthreads();
  if (tid < NCOARSE) stmp[tid] = hist[tid];
  __syncthreads();
  for (int off = 1; off < NCOARSE; off <<= 1) {
    u32 t = 0;
    if (tid < NCOARSE && tid >= off) t = stmp[tid - off];
    __syncthreads();
    if (tid < NCOARSE) stmp[tid] += t;
    __syncthreads();
  }
  if (tid < NCOARSE) lstart[tid] = stmp[tid] - hist[tid];
  __syncthreads();
#pragma unroll
  for (int j = 0; j < 16; j++) {
    u32 bin = recs[j] >> 19;
    staged[lstart[bin] + rr[j]] = recs[j];
  }
  if (tid < NCOARSE) {
    u32 c = hist[tid];
    gbase[tid] = c ? atomicAdd(&cursor[(size_t)g * NCOARSE + tid], c) : 0u;
  }
  __syncthreads();
  u32* bn = binned + (size_t)g * NCOARSE * SLOT;
  for (int s = tid; s < CHUNK; s += 256) {
    u32 v = staged[s];
    u32 bin = v >> 19;
    u32 dst = bin * SLOT + gbase[bin] + ((u32)s - lstart[bin]);
    bn[dst] = v & 0x7FFFFu;  // e | label<<17
  }
}

// exclusive scan of 256 bucket counts per batch -> starts
__global__ __launch_bounds__(256) void scanB_kernel(const u32* __restrict__ cursor, u32* __restrict__ starts) {
  __shared__ u32 stmp[NCOARSE];
  __shared__ u32 cnts[NCOARSE];
  int g = blockIdx.x, tid = threadIdx.x;
  u32 v = cursor[(size_t)g * NCOARSE + tid];
  cnts[tid] = v; stmp[tid] = v;
  __syncthreads();
  for (int off = 1; off < NCOARSE; off <<= 1) {
    u32 t = (tid >= off) ? stmp[tid - off] : 0u;
    __syncthreads();
    stmp[tid] += t;
    __syncthreads();
  }
  starts[(size_t)g * NCOARSE + tid] = stmp[tid] - cnts[tid];
}

// One block handles 8 buckets. Per bucket: counting sub-sort instead of bitonic —
// sub-bin by k1 bits 23..15 (512 LDS sub-bins, Poisson(1)), hist -> scan ->
// scatter -> per-thread exact stable rank of its own sub-bin by full (k1,e).
// position-in-bucket = subbin_excl_start + rank (sub-bin index is a key prefix).
__global__ __launch_bounds__(512) void passB_kernel(const u32* __restrict__ cursor, const u32* __restrict__ starts,
                                                    const u32* __restrict__ binned, u32* __restrict__ EL,
                                                    u32* __restrict__ posh, u32* __restrict__ negh, int batch0) {
  __shared__ u32 sk1[2], sk2[2];
  __shared__ u64 keys[SLOT];
  __shared__ u32 hist[NSUB];
  __shared__ u32 sstart[NSUB];
  __shared__ u32 lpos[NCOARSE], lneg[NCOARSE];
  int g = blockIdx.y;
  int tid = threadIdx.x;
  if (tid == 0) {
    u32 a, c;
    batch_round_key(batch0 + g, 1, a, c); sk1[0] = a; sk1[1] = c;
    batch_round_key(batch0 + g, 2, a, c); sk2[0] = a; sk2[1] = c;
  }
  if (tid < NCOARSE) { lpos[tid] = 0; lneg[tid] = 0; }
  __syncthreads();
  const u32* bn = binned + (size_t)g * NCOARSE * SLOT;
  u32* el = EL + (size_t)g * NN;
  for (int q = 0; q < 8; q++) {
    u32 bin = blockIdx.x * 8 + q;
    u32 cnt = cursor[(size_t)g * NCOARSE + bin];
    if (cnt > SLOT) cnt = SLOT;
    u32 start = starts[(size_t)g * NCOARSE + bin];
    hist[tid] = 0;
    __syncthreads();
    // load + sub-bin histogram; keep key/sub/rank-ticket in registers
    u64 mykey[2]; u32 mysr[2];
#pragma unroll
    for (int t = 0; t < 2; t++) {
      int i = tid + t * 512;
      if (i < (int)cnt) {
        u32 v = bn[bin * SLOT + i];
        u32 e = v & EMASK17;
        u32 k1 = tf_bits(sk1[0], sk1[1], e);
        mykey[t] = ((u64)k1 << 19) | ((u64)e << 2) | (u64)(v >> 17);  // k1 | e | label
        u32 sub = (k1 >> 15) & 0x1FFu;
        u32 r = atomicAdd(&hist[sub], 1u);
        mysr[t] = (sub << 9) | r;  // r < 512 always (occupancy ~1)
      } else {
        mysr[t] = 0xFFFFFFFFu;
      }
    }
    __syncthreads();
    // exclusive scan of hist over 512 sub-bins
    u32 h = hist[tid];
    sstart[tid] = h;
    __syncthreads();
    for (int off = 1; off < NSUB; off <<= 1) {
      u32 t2 = (tid >= off) ? sstart[tid - off] : 0u;
      __syncthreads();
      sstart[tid] += t2;
      __syncthreads();
    }
    u32 myexcl = sstart[tid] - h;
    __syncthreads();
    sstart[tid] = myexcl;
    __syncthreads();
    // scatter into sub-bin-grouped order
#pragma unroll
    for (int t = 0; t < 2; t++) {
      if (mysr[t] != 0xFFFFFFFFu)
        keys[sstart[mysr[t] >> 9] + (mysr[t] & 0x1FFu)] = mykey[t];
    }
    __syncthreads();
    // exact stable rank of own sub-bin (compare full (k1,e); e unique)
    for (u32 i = 0; i < h; i++) {
      u64 ki = keys[myexcl + i];
      u32 r = 0;
      for (u32 j = 0; j < h; j++) {
        if (j != i && keys[myexcl + j] < ki) r++;
      }
      u32 p1 = start + myexcl + r;
      u32 e = (u32)(ki >> 2) & EMASK17;
      u32 label = (u32)ki & 3u;
      el[p1] = e | (label << 17);
      if (label) {
        u32 k2 = tf_bits(sk2[0], sk2[1], p1);
        if (label == 1) atomicAdd(&lpos[k2 >> 24], 1u);
        else atomicAdd(&lneg[k2 >> 24], 1u);
      }
    }
    __syncthreads();
  }
  if (tid < NCOARSE) {
    if (lpos[tid]) atomicAdd(&posh[(size_t)g * NCOARSE + tid], lpos[tid]);
  } else {
    int t = tid - NCOARSE;
    if (lneg[t]) atomicAdd(&negh[(size_t)g * NCOARSE + t], lneg[t]);
  }
}

// Per batch: qp = min(128,np), qn = 512-qp; threshold bins over 256-bin hists.
__global__ __launch_bounds__(256) void threshold_kernel(const u32* __restrict__ posh,
                                                        const u32* __restrict__ negh,
                                                        u32* __restrict__ params) {
  int g = blockIdx.x, tid = threadIdx.x;
  __shared__ u32 rp[NCOARSE], rn[NCOARSE];
  rp[tid] = posh[(size_t)g * NCOARSE + tid];
  rn[tid] = negh[(size_t)g * NCOARSE + tid];
  __syncthreads();
  if (tid == 0) {
    u32 np = 0;
    for (int i = 0; i < NCOARSE; i++) np += rp[i];
    u32 qp = np < 128 ? np : 128;
    u32 qn = 512 - qp;
    u32 tp = 256;
    if (qp > 0) {
      u32 cum = 0;
      for (int i = 255; i >= 0; i--) { cum += rp[i]; if (cum >= qp) { tp = (u32)i; break; } }
    }
    u32 tn = 0, cum = 0;
    for (int i = 255; i >= 0; i--) { cum += rn[i]; if (cum >= qn) { tn = (u32)i; break; } }
    u32* pr = params + (size_t)g * 4;
    pr[0] = tp; pr[1] = tn; pr[2] = qp; pr[3] = qn;
  }
}

// Coalesced grid-stride pass over EL: recompute k2 from p1, collect threshold
// survivors. Grid is (32, G) = 2048 wgs — NOT 32768: the CP workgroup-dispatch
// rate (~60-95 wg/us observed R2-R5) floors any 32k-wg kernel at ~350-550 us.
__global__ __launch_bounds__(256) void collect_kernel(const u32* __restrict__ EL, const u32* __restrict__ params,
                                                      u32* __restrict__ cnt, u64* __restrict__ poskey,
                                                      u32* __restrict__ posval, u64* __restrict__ negkey,
                                                      u32* __restrict__ negval, int batch0) {
  __shared__ u32 sk[2];
  __shared__ u32 sp[2];
  int g = blockIdx.y;
  if (threadIdx.x == 0) {
    u32 k0, k1; batch_round_key(batch0 + g, 2, k0, k1); sk[0] = k0; sk[1] = k1;
    const u32* pr = params + (size_t)g * 4; sp[0] = pr[0]; sp[1] = pr[1];
  }
  __syncthreads();
  const uint4* el4 = (const uint4*)(EL + (size_t)g * NN);
#pragma unroll
  for (int c = 0; c < 4; c++) {
    u32 i4 = blockIdx.x * 1024 + c * 256 + threadIdx.x;  // uint4 index
    uint4 v4 = el4[i4];
#pragma unroll
    for (int m = 0; m < 4; m++) {
      u32 val = (&v4.x)[m];
      u32 label = val >> 17;
      if (!label) continue;
      u32 p1 = i4 * 4 + m;
      u32 k2 = tf_bits(sk[0], sk[1], p1);
      if (label == 1) {
        if ((k2 >> 24) >= sp[0]) {
          u32 s = atomicAdd(&cnt[(size_t)g * 2], 1u);
          if (s < CAP) { poskey[(size_t)g * CAP + s] = ((u64)k2 << 32) | p1; posval[(size_t)g * CAP + s] = val; }
        }
      } else {
        if ((k2 >> 24) >= sp[1]) {
          u32 s = atomicAdd(&cnt[(size_t)g * 2 + 1], 1u);
          if (s < CAP) { negkey[(size_t)g * CAP + s] = ((u64)k2 << 32) | p1; negval[(size_t)g * CAP + s] = val; }
        }
      }
    }
  }
}

// Per batch: exact top-qp / top-qn by (k2,p1) desc over collected, then 512
// ascending index sort -> output.
__global__ __launch_bounds__(1024) void select_final_kernel(const u32* __restrict__ params,
                                                            const u32* __restrict__ cnt,
                                                            const u64* __restrict__ poskey,
                                                            const u32* __restrict__ posval,
                                                            const u64* __restrict__ negkey,
                                                            const u32* __restrict__ negval,
                                                            int* __restrict__ out, int batch0) {
  int g = blockIdx.x, tid = threadIdx.x, b = batch0 + g;
  __shared__ u64 skey[1024];
  __shared__ u32 sval[1024];
  __shared__ int sel[512];
  const u32* pr = params + (size_t)g * 4;
  u32 qp = pr[2], qn = pr[3];
  u32 cp = cnt[(size_t)g * 2]; if (cp > CAP) cp = CAP;
  u32 cn = cnt[(size_t)g * 2 + 1]; if (cn > CAP) cn = CAP;
  if (tid < 512) sel[tid] = 0;

  skey[tid] = (tid < (int)cp) ? poskey[(size_t)g * CAP + tid] : 0ull;
  sval[tid] = (tid < (int)cp) ? posval[(size_t)g * CAP + tid] : 0u;
  __syncthreads();
  for (int k = 2; k <= 1024; k <<= 1)
    for (int s = k >> 1; s > 0; s >>= 1) {
      if (tid < 512) {
        int i = ((tid & ~(s - 1)) << 1) | (tid & (s - 1));
        int j = i | s;
        bool up = ((i & k) == 0);
        if ((skey[i] < skey[j]) == up) {
          u64 tk = skey[i]; skey[i] = skey[j]; skey[j] = tk;
          u32 tv = sval[i]; sval[i] = sval[j]; sval[j] = tv;
        }
      }
      __syncthreads();
    }
  if (tid < (int)qp) sel[tid] = (int)(sval[tid] & EMASK17);
  __syncthreads();

  skey[tid] = (tid < (int)cn) ? negkey[(size_t)g * CAP + tid] : 0ull;
  sval[tid] = (tid < (int)cn) ? negval[(size_t)g * CAP + tid] : 0u;
  __syncthreads();
  for (int k = 2; k <= 1024; k <<= 1)
    for (int s = k >> 1; s > 0; s >>= 1) {
      if (tid < 512) {
        int i = ((tid & ~(s - 1)) << 1) | (tid & (s - 1));
        int j = i | s;
        bool up = ((i & k) == 0);
        if ((skey[i] < skey[j]) == up) {
          u64 tk = skey[i]; skey[i] = skey[j]; skey[j] = tk;
          u32 tv = sval[i]; sval[i] = sval[j]; sval[j] = tv;
        }
      }
      __syncthreads();
    }
  if (tid < (int)qn) sel[qp + tid] = (int)(sval[tid] & EMASK17);
  __syncthreads();

  for (int k = 2; k <= 512; k <<= 1)
    for (int s = k >> 1; s > 0; s >>= 1) {
      if (tid < 256) {
        int i = ((tid & ~(s - 1)) << 1) | (tid & (s - 1));
        int j = i | s;
        bool up = ((i & k) == 0);
        int a = sel[i], c = sel[j];
        if ((a > c) == up) { sel[i] = c; sel[j] = a; }
      }
      __syncthreads();
    }
  if (tid < 512) out[(size_t)b * 512 + tid] = sel[tid];
}

extern "C" void kernel_launch(void* const* d_in, const int* in_sizes, int n_in,
                              void* d_out, int out_size, void* d_ws, size_t ws_size,
                              hipStream_t stream) {
  const int* pos = (const int*)d_in[0];
  const int* neg = (const int*)d_in[1];
  const int* ign = (const int*)d_in[2];
  int* out = (int*)d_out;

  // per-batch ws: zero-region (cursor 1KB + posh 1KB + negh 1KB + cnt 8B)
  //             + binned 1MB + EL 512KB + starts 1KB + params 16B + CAP arrays 24KB
  size_t zeroPer = (NCOARSE * 3 + 2) * 4;
  size_t perBatch = zeroPer + (size_t)NCOARSE * SLOT * 4 + (size_t)NN * 4 + NCOARSE * 4 + 16 +
                    (size_t)CAP * (8 + 8 + 4 + 4);
  int G = (int)(ws_size / perBatch);
  if (G > BATCH) G = BATCH;
  if (G < 1) G = 1;

  char* p = (char*)d_ws;
  u32* cursor = (u32*)p;            p += (size_t)G * NCOARSE * 4;
  u32* posh = (u32*)p;              p += (size_t)G * NCOARSE * 4;
  u32* negh = (u32*)p;              p += (size_t)G * NCOARSE * 4;
  u32* cnt = (u32*)p;               p += (size_t)G * 2 * 4;
  size_t zeroBytes = (size_t)p - (size_t)d_ws;
  u32* binned = (u32*)p;            p += (size_t)G * NCOARSE * SLOT * 4;
  u32* EL = (u32*)p;                p += (size_t)G * NN * 4;
  u32* starts = (u32*)p;            p += (size_t)G * NCOARSE * 4;
  u32* params = (u32*)p;            p += (size_t)G * 4 * 4;
  u64* poskey = (u64*)p;            p += (size_t)G * CAP * 8;
  u64* negkey = (u64*)p;            p += (size_t)G * CAP * 8;
  u32* posval = (u32*)p;            p += (size_t)G * CAP * 4;
  u32* negval = (u32*)p;            p += (size_t)G * CAP * 4;

  for (int batch0 = 0; batch0 < BATCH; batch0 += G) {
    int Gi = (BATCH - batch0 < G) ? (BATCH - batch0) : G;
    hipMemsetAsync(d_ws, 0, zeroBytes, stream);
    dim3 gridS(NN / CHUNK, Gi);
    scatterA_kernel<<<gridS, 256, 0, stream>>>(cursor, binned, pos, neg, ign, batch0);
    scanB_kernel<<<Gi, 256, 0, stream>>>(cursor, starts);
    dim3 gridP(NCOARSE / 8, Gi);
    passB_kernel<<<gridP, 512, 0, stream>>>(cursor, starts, binned, EL, posh, negh, batch0);
    threshold_kernel<<<Gi, 256, 0, stream>>>(posh, negh, params);
    dim3 gridC(NN / CHUNK, Gi);  // 32 x G blocks, 4096 elems per block
    collect_kernel<<<gridC, 256, 0, stream>>>(EL, params, cnt, poskey, posval, negkey, negval, batch0);
    select_final_kernel<<<Gi, 1024, 0, stream>>>(params, cnt, poskey, posval, negkey, negval, out, batch0);
  }
}

// Round 7
// 421.164 us; speedup vs baseline: 6.6187x; 1.1151x over previous
//
#include <hip/hip_runtime.h>
#include <stdint.h>

#define BATCH 64
#define NN 131072
#define NCOARSE 256
#define SLOT 1024
#define CHUNK 4096
#define NSUB 512
#define EMASK17 0x1FFFFu
#define CAP 1024

typedef uint32_t u32;
typedef uint64_t u64;

__device__ __forceinline__ u32 rotl32(u32 v, int d) { return (v << d) | (v >> (32 - d)); }

// Exact port of JAX threefry2x32 block cipher
__device__ __forceinline__ void threefry2x32(u32 k0, u32 k1, u32 x0, u32 x1, u32& o0, u32& o1) {
  u32 ks2 = k0 ^ k1 ^ 0x1BD11BDAu;
  x0 += k0; x1 += k1;
#define TF_R(r) { x0 += x1; x1 = rotl32(x1, r); x1 ^= x0; }
  TF_R(13) TF_R(15) TF_R(26) TF_R(6)
  x0 += k1;  x1 += ks2 + 1u;
  TF_R(17) TF_R(29) TF_R(16) TF_R(24)
  x0 += ks2; x1 += k0 + 2u;
  TF_R(13) TF_R(15) TF_R(26) TF_R(6)
  x0 += k0;  x1 += k1 + 3u;
  TF_R(17) TF_R(29) TF_R(16) TF_R(24)
  x0 += k1;  x1 += ks2 + 4u;
  TF_R(13) TF_R(15) TF_R(26) TF_R(6)
  x0 += ks2; x1 += k0 + 5u;
#undef TF_R
  o0 = x0; o1 = x1;
}

// threefry_partitionable: bits[i] = o0 ^ o1 of cipher(key, (0, i))
__device__ __forceinline__ u32 tf_bits(u32 k0, u32 k1, u32 i) {
  u32 o0, o1;
  threefry2x32(k0, k1, 0u, i, o0, o1);
  return o0 ^ o1;
}

// kb = cipher((0,42),(0,b)); round1 sub = cipher(kb,(0,1));
// round2 sub = cipher(cipher(kb,(0,0)),(0,1))
__device__ void batch_round_key(int b, int round, u32& rk0, u32& rk1) {
  u32 kb0, kb1;
  threefry2x32(0u, 42u, 0u, (u32)b, kb0, kb1);
  if (round == 1) { threefry2x32(kb0, kb1, 0u, 1u, rk0, rk1); return; }
  u32 c0, c1;
  threefry2x32(kb0, kb1, 0u, 0u, c0, c1);
  threefry2x32(c0, c1, 0u, 1u, rk0, rk1);
}

// Coarse bucket scatter with LDS staging: bins by k1>>24 into 1024-slot regions.
// Stores the FULL u64 sort key (k1<<19 | e<<2 | label) so passB never recomputes
// k1 (k1 threefry was 60% of passB's VALU in R6). Within-bucket order irrelevant:
// passB does the exact stable re-sort.
__global__ __launch_bounds__(256) void scatterA_kernel(u32* __restrict__ cursor, u64* __restrict__ binned,
                                                       const int* __restrict__ posg, const int* __restrict__ negg,
                                                       const int* __restrict__ igng, int batch0) {
  __shared__ u32 sk[2];
  __shared__ u32 hist[NCOARSE];
  __shared__ u32 lstart[NCOARSE];
  __shared__ u32 gbase[NCOARSE];
  __shared__ u64 staged[CHUNK];
  __shared__ u32 stmp[NCOARSE];
  int g = blockIdx.y;
  int b = batch0 + g;
  int tid = threadIdx.x;
  if (tid == 0) { u32 k0, k1; batch_round_key(b, 1, k0, k1); sk[0] = k0; sk[1] = k1; }
  if (tid < NCOARSE) hist[tid] = 0;
  __syncthreads();
  u32 base = blockIdx.x * CHUNK;
  u64 recs[16]; u32 rr[16];
  const int4* P4 = (const int4*)(posg + (size_t)b * NN);
  const int4* Q4 = (const int4*)(negg + (size_t)b * NN);
  const int4* I4 = (const int4*)(igng + (size_t)b * NN);
#pragma unroll
  for (int j = 0; j < 4; j++) {
    u32 e0 = base + j * 1024 + tid * 4;
    int4 pv = P4[e0 >> 2];
    int4 nv = Q4[e0 >> 2];
    int4 iv = I4[e0 >> 2];
#pragma unroll
    for (int m = 0; m < 4; m++) {
      u32 e = e0 + m;
      int p = (&pv.x)[m] != 0, n = (&nv.x)[m] != 0, ig = (&iv.x)[m] != 0;
      u32 label = ((p | n) && !ig) ? (p ? 1u : 2u) : 0u;
      u32 k1 = tf_bits(sk[0], sk[1], e);
      u32 bin = k1 >> 24;
      rr[j * 4 + m] = atomicAdd(&hist[bin], 1u);
      recs[j * 4 + m] = ((u64)k1 << 19) | ((u64)e << 2) | (u64)label;
    }
  }
  __syncthreads();
  if (tid < NCOARSE) stmp[tid] = hist[tid];
  __syncthreads();
  for (int off = 1; off < NCOARSE; off <<= 1) {
    u32 t = 0;
    if (tid < NCOARSE && tid >= off) t = stmp[tid - off];
    __syncthreads();
    if (tid < NCOARSE) stmp[tid] += t;
    __syncthreads();
  }
  if (tid < NCOARSE) lstart[tid] = stmp[tid] - hist[tid];
  __syncthreads();
#pragma unroll
  for (int j = 0; j < 16; j++) {
    u32 bin = (u32)(recs[j] >> 43);
    staged[lstart[bin] + rr[j]] = recs[j];
  }
  if (tid < NCOARSE) {
    u32 c = hist[tid];
    gbase[tid] = c ? atomicAdd(&cursor[(size_t)g * NCOARSE + tid], c) : 0u;
  }
  __syncthreads();
  u64* bn = binned + (size_t)g * NCOARSE * SLOT;
  for (int s = tid; s < CHUNK; s += 256) {
    u64 v = staged[s];
    u32 bin = (u32)(v >> 43);
    u32 dst = bin * SLOT + gbase[bin] + ((u32)s - lstart[bin]);
    bn[dst] = v;
  }
}

// exclusive scan of 256 bucket counts per batch -> starts
__global__ __launch_bounds__(256) void scanB_kernel(const u32* __restrict__ cursor, u32* __restrict__ starts) {
  __shared__ u32 stmp[NCOARSE];
  __shared__ u32 cnts[NCOARSE];
  int g = blockIdx.x, tid = threadIdx.x;
  u32 v = cursor[(size_t)g * NCOARSE + tid];
  cnts[tid] = v; stmp[tid] = v;
  __syncthreads();
  for (int off = 1; off < NCOARSE; off <<= 1) {
    u32 t = (tid >= off) ? stmp[tid - off] : 0u;
    __syncthreads();
    stmp[tid] += t;
    __syncthreads();
  }
  starts[(size_t)g * NCOARSE + tid] = stmp[tid] - cnts[tid];
}

// One block handles 8 buckets. Per bucket: counting sub-sort — sub-bin by k1
// bits 23..15 (key bits 42..34; 512 LDS sub-bins, Poisson(1)), shfl-scan (2
// barriers, not 18), LDS scatter, per-thread exact stable rank of its own
// sub-bin by full u64 key (e unique => stable). Writes EL[p1] = k2<<32|e<<2|label
// so collect needs no threefry. k2 pos/neg histograms accumulated in LDS.
__global__ __launch_bounds__(512) void passB_kernel(const u32* __restrict__ cursor, const u32* __restrict__ starts,
                                                    const u64* __restrict__ binned, u64* __restrict__ EL,
                                                    u32* __restrict__ posh, u32* __restrict__ negh, int batch0) {
  __shared__ u32 sk2[2];
  __shared__ u64 keys[SLOT];
  __shared__ u32 hist[NSUB];
  __shared__ u32 sstart[NSUB];
  __shared__ u32 wtot[8];
  __shared__ u32 lpos[NCOARSE], lneg[NCOARSE];
  int g = blockIdx.y;
  int tid = threadIdx.x;
  if (tid == 0) {
    u32 a, c;
    batch_round_key(batch0 + g, 2, a, c); sk2[0] = a; sk2[1] = c;
  }
  if (tid < NCOARSE) { lpos[tid] = 0; lneg[tid] = 0; }
  __syncthreads();
  const u64* bn = binned + (size_t)g * NCOARSE * SLOT;
  u64* el = EL + (size_t)g * NN;
  for (int q = 0; q < 8; q++) {
    u32 bin = blockIdx.x * 8 + q;
    u32 cnt = cursor[(size_t)g * NCOARSE + bin];
    if (cnt > SLOT) cnt = SLOT;
    u32 start = starts[(size_t)g * NCOARSE + bin];
    hist[tid] = 0;
    __syncthreads();
    // load full keys; sub-bin histogram; keep key/ticket in registers
    u64 mykey[2]; u32 mysr[2];
#pragma unroll
    for (int t = 0; t < 2; t++) {
      int i = tid + t * 512;
      if (i < (int)cnt) {
        u64 key = bn[bin * SLOT + i];
        u32 sub = (u32)(key >> 34) & 0x1FFu;
        u32 r = atomicAdd(&hist[sub], 1u);
        mykey[t] = key;
        mysr[t] = (sub << 9) | r;
      } else {
        mysr[t] = 0xFFFFFFFFu;
      }
    }
    __syncthreads();
    // exclusive scan of hist over 512 sub-bins: wave shfl-scan + wave-total fixup
    u32 h = hist[tid];
    u32 v = h;
#pragma unroll
    for (int off = 1; off < 64; off <<= 1) {
      u32 t2 = __shfl_up(v, off, 64);
      if ((tid & 63) >= off) v += t2;
    }
    if ((tid & 63) == 63) wtot[tid >> 6] = v;
    __syncthreads();
    u32 woff = 0;
    for (int w = 0; w < (tid >> 6); w++) woff += wtot[w];
    u32 myexcl = v + woff - h;
    sstart[tid] = myexcl;
    __syncthreads();
    // scatter into sub-bin-grouped order
#pragma unroll
    for (int t = 0; t < 2; t++) {
      if (mysr[t] != 0xFFFFFFFFu)
        keys[sstart[mysr[t] >> 9] + (mysr[t] & 0x1FFu)] = mykey[t];
    }
    __syncthreads();
    // exact stable rank of own sub-bin (full u64 compare; e unique)
    for (u32 i = 0; i < h; i++) {
      u64 ki = keys[myexcl + i];
      u32 r = 0;
      for (u32 j = 0; j < h; j++) {
        if (j != i && keys[myexcl + j] < ki) r++;
      }
      u32 p1 = start + myexcl + r;
      u32 e = (u32)(ki >> 2) & EMASK17;
      u32 label = (u32)ki & 3u;
      u32 k2 = 0;
      if (label) {
        k2 = tf_bits(sk2[0], sk2[1], p1);
        if (label == 1) atomicAdd(&lpos[k2 >> 24], 1u);
        else atomicAdd(&lneg[k2 >> 24], 1u);
      }
      el[p1] = ((u64)k2 << 32) | ((u64)e << 2) | (u64)label;
    }
    __syncthreads();
  }
  if (tid < NCOARSE) {
    if (lpos[tid]) atomicAdd(&posh[(size_t)g * NCOARSE + tid], lpos[tid]);
  } else {
    int t = tid - NCOARSE;
    if (lneg[t]) atomicAdd(&negh[(size_t)g * NCOARSE + t], lneg[t]);
  }
}

// Per batch: qp = min(128,np), qn = 512-qp; threshold bins over 256-bin hists.
__global__ __launch_bounds__(256) void threshold_kernel(const u32* __restrict__ posh,
                                                        const u32* __restrict__ negh,
                                                        u32* __restrict__ params) {
  int g = blockIdx.x, tid = threadIdx.x;
  __shared__ u32 rp[NCOARSE], rn[NCOARSE];
  rp[tid] = posh[(size_t)g * NCOARSE + tid];
  rn[tid] = negh[(size_t)g * NCOARSE + tid];
  __syncthreads();
  if (tid == 0) {
    u32 np = 0;
    for (int i = 0; i < NCOARSE; i++) np += rp[i];
    u32 qp = np < 128 ? np : 128;
    u32 qn = 512 - qp;
    u32 tp = 256;
    if (qp > 0) {
      u32 cum = 0;
      for (int i = 255; i >= 0; i--) { cum += rp[i]; if (cum >= qp) { tp = (u32)i; break; } }
    }
    u32 tn = 0, cum = 0;
    for (int i = 255; i >= 0; i--) { cum += rn[i]; if (cum >= qn) { tn = (u32)i; break; } }
    u32* pr = params + (size_t)g * 4;
    pr[0] = tp; pr[1] = tn; pr[2] = qp; pr[3] = qn;
  }
}

// Memory-bound threshold filter over EL (k2 precomputed by passB — no threefry).
// Grid (32, G) = 2048 wgs (CP dispatch-rate floor ~60-95 wg/us, R2-R6).
__global__ __launch_bounds__(256) void collect_kernel(const u64* __restrict__ EL, const u32* __restrict__ params,
                                                      u32* __restrict__ cnt, u64* __restrict__ poskey,
                                                      u32* __restrict__ posval, u64* __restrict__ negkey,
                                                      u32* __restrict__ negval, int batch0) {
  __shared__ u32 sp[2];
  int g = blockIdx.y;
  if (threadIdx.x == 0) {
    const u32* pr = params + (size_t)g * 4; sp[0] = pr[0]; sp[1] = pr[1];
  }
  __syncthreads();
  const u64* el = EL + (size_t)g * NN;
#pragma unroll
  for (int c = 0; c < 16; c++) {
    u32 p1 = blockIdx.x * CHUNK + c * 256 + threadIdx.x;
    u64 v = el[p1];
    u32 label = (u32)v & 3u;
    if (!label) continue;
    u32 k2 = (u32)(v >> 32);
    u32 val = ((u32)(v >> 2) & EMASK17) | (label << 17);
    if (label == 1) {
      if ((k2 >> 24) >= sp[0]) {
        u32 s = atomicAdd(&cnt[(size_t)g * 2], 1u);
        if (s < CAP) { poskey[(size_t)g * CAP + s] = ((u64)k2 << 32) | p1; posval[(size_t)g * CAP + s] = val; }
      }
    } else {
      if ((k2 >> 24) >= sp[1]) {
        u32 s = atomicAdd(&cnt[(size_t)g * 2 + 1], 1u);
        if (s < CAP) { negkey[(size_t)g * CAP + s] = ((u64)k2 << 32) | p1; negval[(size_t)g * CAP + s] = val; }
      }
    }
  }
}

// Per batch: exact top-qp / top-qn by (k2,p1) desc over collected, then 512
// ascending index sort -> output.
__global__ __launch_bounds__(1024) void select_final_kernel(const u32* __restrict__ params,
                                                            const u32* __restrict__ cnt,
                                                            const u64* __restrict__ poskey,
                                                            const u32* __restrict__ posval,
                                                            const u64* __restrict__ negkey,
                                                            const u32* __restrict__ negval,
                                                            int* __restrict__ out, int batch0) {
  int g = blockIdx.x, tid = threadIdx.x, b = batch0 + g;
  __shared__ u64 skey[1024];
  __shared__ u32 sval[1024];
  __shared__ int sel[512];
  const u32* pr = params + (size_t)g * 4;
  u32 qp = pr[2], qn = pr[3];
  u32 cp = cnt[(size_t)g * 2]; if (cp > CAP) cp = CAP;
  u32 cn = cnt[(size_t)g * 2 + 1]; if (cn > CAP) cn = CAP;
  if (tid < 512) sel[tid] = 0;

  skey[tid] = (tid < (int)cp) ? poskey[(size_t)g * CAP + tid] : 0ull;
  sval[tid] = (tid < (int)cp) ? posval[(size_t)g * CAP + tid] : 0u;
  __syncthreads();
  for (int k = 2; k <= 1024; k <<= 1)
    for (int s = k >> 1; s > 0; s >>= 1) {
      if (tid < 512) {
        int i = ((tid & ~(s - 1)) << 1) | (tid & (s - 1));
        int j = i | s;
        bool up = ((i & k) == 0);
        if ((skey[i] < skey[j]) == up) {
          u64 tk = skey[i]; skey[i] = skey[j]; skey[j] = tk;
          u32 tv = sval[i]; sval[i] = sval[j]; sval[j] = tv;
        }
      }
      __syncthreads();
    }
  if (tid < (int)qp) sel[tid] = (int)(sval[tid] & EMASK17);
  __syncthreads();

  skey[tid] = (tid < (int)cn) ? negkey[(size_t)g * CAP + tid] : 0ull;
  sval[tid] = (tid < (int)cn) ? negval[(size_t)g * CAP + tid] : 0u;
  __syncthreads();
  for (int k = 2; k <= 1024; k <<= 1)
    for (int s = k >> 1; s > 0; s >>= 1) {
      if (tid < 512) {
        int i = ((tid & ~(s - 1)) << 1) | (tid & (s - 1));
        int j = i | s;
        bool up = ((i & k) == 0);
        if ((skey[i] < skey[j]) == up) {
          u64 tk = skey[i]; skey[i] = skey[j]; skey[j] = tk;
          u32 tv = sval[i]; sval[i] = sval[j]; sval[j] = tv;
        }
      }
      __syncthreads();
    }
  if (tid < (int)qn) sel[qp + tid] = (int)(sval[tid] & EMASK17);
  __syncthreads();

  for (int k = 2; k <= 512; k <<= 1)
    for (int s = k >> 1; s > 0; s >>= 1) {
      if (tid < 256) {
        int i = ((tid & ~(s - 1)) << 1) | (tid & (s - 1));
        int j = i | s;
        bool up = ((i & k) == 0);
        int a = sel[i], c = sel[j];
        if ((a > c) == up) { sel[i] = c; sel[j] = a; }
      }
      __syncthreads();
    }
  if (tid < 512) out[(size_t)b * 512 + tid] = sel[tid];
}

extern "C" void kernel_launch(void* const* d_in, const int* in_sizes, int n_in,
                              void* d_out, int out_size, void* d_ws, size_t ws_size,
                              hipStream_t stream) {
  const int* pos = (const int*)d_in[0];
  const int* neg = (const int*)d_in[1];
  const int* ign = (const int*)d_in[2];
  int* out = (int*)d_out;

  // per-batch ws: zero-region (cursor 1KB + posh 1KB + negh 1KB + cnt 8B)
  //             + binned 2MB (u64) + EL 1MB (u64) + starts 1KB + params 16B + CAP arrays 24KB
  size_t zeroPer = (NCOARSE * 3 + 2) * 4;
  size_t perBatch = zeroPer + (size_t)NCOARSE * SLOT * 8 + (size_t)NN * 8 + NCOARSE * 4 + 16 +
                    (size_t)CAP * (8 + 8 + 4 + 4);
  int G = (int)(ws_size / perBatch);
  if (G > BATCH) G = BATCH;
  if (G < 1) G = 1;

  char* p = (char*)d_ws;
  u32* cursor = (u32*)p;            p += (size_t)G * NCOARSE * 4;
  u32* posh = (u32*)p;              p += (size_t)G * NCOARSE * 4;
  u32* negh = (u32*)p;              p += (size_t)G * NCOARSE * 4;
  u32* cnt = (u32*)p;               p += (size_t)G * 2 * 4;
  size_t zeroBytes = (size_t)p - (size_t)d_ws;
  u64* binned = (u64*)p;            p += (size_t)G * NCOARSE * SLOT * 8;
  u64* EL = (u64*)p;                p += (size_t)G * NN * 8;
  u32* starts = (u32*)p;            p += (size_t)G * NCOARSE * 4;
  u32* params = (u32*)p;            p += (size_t)G * 4 * 4;
  u64* poskey = (u64*)p;            p += (size_t)G * CAP * 8;
  u64* negkey = (u64*)p;            p += (size_t)G * CAP * 8;
  u32* posval = (u32*)p;            p += (size_t)G * CAP * 4;
  u32* negval = (u32*)p;            p += (size_t)G * CAP * 4;

  for (int batch0 = 0; batch0 < BATCH; batch0 += G) {
    int Gi = (BATCH - batch0 < G) ? (BATCH - batch0) : G;
    hipMemsetAsync(d_ws, 0, zeroBytes, stream);
    dim3 gridS(NN / CHUNK, Gi);
    scatterA_kernel<<<gridS, 256, 0, stream>>>(cursor, binned, pos, neg, ign, batch0);
    scanB_kernel<<<Gi, 256, 0, stream>>>(cursor, starts);
    dim3 gridP(NCOARSE / 8, Gi);
    passB_kernel<<<gridP, 512, 0, stream>>>(cursor, starts, binned, EL, posh, negh, batch0);
    threshold_kernel<<<Gi, 256, 0, stream>>>(posh, negh, params);
    dim3 gridC(NN / CHUNK, Gi);
    collect_kernel<<<gridC, 256, 0, stream>>>(EL, params, cnt, poskey, posval, negkey, negval, batch0);
    select_final_kernel<<<Gi, 1024, 0, stream>>>(params, cnt, poskey, posval, negkey, negval, out, batch0);
  }
}

// Round 8
// 358.011 us; speedup vs baseline: 7.7862x; 1.1764x over previous
//
#include <hip/hip_runtime.h>
#include <stdint.h>

#define BATCH 64
#define NN 131072
#define NCOARSE 256
#define SLOT 1024
#define CHUNK 4096
#define NSUB 1024
#define EMASK17 0x1FFFFu
#define CAP 1024

typedef uint32_t u32;
typedef uint64_t u64;

__device__ __forceinline__ u32 rotl32(u32 v, int d) { return (v << d) | (v >> (32 - d)); }

// Exact port of JAX threefry2x32 block cipher
__device__ __forceinline__ void threefry2x32(u32 k0, u32 k1, u32 x0, u32 x1, u32& o0, u32& o1) {
  u32 ks2 = k0 ^ k1 ^ 0x1BD11BDAu;
  x0 += k0; x1 += k1;
#define TF_R(r) { x0 += x1; x1 = rotl32(x1, r); x1 ^= x0; }
  TF_R(13) TF_R(15) TF_R(26) TF_R(6)
  x0 += k1;  x1 += ks2 + 1u;
  TF_R(17) TF_R(29) TF_R(16) TF_R(24)
  x0 += ks2; x1 += k0 + 2u;
  TF_R(13) TF_R(15) TF_R(26) TF_R(6)
  x0 += k0;  x1 += k1 + 3u;
  TF_R(17) TF_R(29) TF_R(16) TF_R(24)
  x0 += k1;  x1 += ks2 + 4u;
  TF_R(13) TF_R(15) TF_R(26) TF_R(6)
  x0 += ks2; x1 += k0 + 5u;
#undef TF_R
  o0 = x0; o1 = x1;
}

// threefry_partitionable: bits[i] = o0 ^ o1 of cipher(key, (0, i))
__device__ __forceinline__ u32 tf_bits(u32 k0, u32 k1, u32 i) {
  u32 o0, o1;
  threefry2x32(k0, k1, 0u, i, o0, o1);
  return o0 ^ o1;
}

// kb = cipher((0,42),(0,b)); round1 sub = cipher(kb,(0,1));
// round2 sub = cipher(cipher(kb,(0,0)),(0,1))
__device__ void batch_round_key(int b, int round, u32& rk0, u32& rk1) {
  u32 kb0, kb1;
  threefry2x32(0u, 42u, 0u, (u32)b, kb0, kb1);
  if (round == 1) { threefry2x32(kb0, kb1, 0u, 1u, rk0, rk1); return; }
  u32 c0, c1;
  threefry2x32(kb0, kb1, 0u, 0u, c0, c1);
  threefry2x32(c0, c1, 0u, 1u, rk0, rk1);
}

// Coarse bucket scatter with LDS staging: bins by k1>>24 into 1024-slot regions.
// Stores the FULL u64 sort key (k1<<19 | e<<2 | label) so passB never recomputes k1.
__global__ __launch_bounds__(256) void scatterA_kernel(u32* __restrict__ cursor, u64* __restrict__ binned,
                                                       const int* __restrict__ posg, const int* __restrict__ negg,
                                                       const int* __restrict__ igng, int batch0) {
  __shared__ u32 sk[2];
  __shared__ u32 hist[NCOARSE];
  __shared__ u32 lstart[NCOARSE];
  __shared__ u32 gbase[NCOARSE];
  __shared__ u64 staged[CHUNK];
  __shared__ u32 stmp[NCOARSE];
  int g = blockIdx.y;
  int b = batch0 + g;
  int tid = threadIdx.x;
  if (tid == 0) { u32 k0, k1; batch_round_key(b, 1, k0, k1); sk[0] = k0; sk[1] = k1; }
  if (tid < NCOARSE) hist[tid] = 0;
  __syncthreads();
  u32 base = blockIdx.x * CHUNK;
  u64 recs[16]; u32 rr[16];
  const int4* P4 = (const int4*)(posg + (size_t)b * NN);
  const int4* Q4 = (const int4*)(negg + (size_t)b * NN);
  const int4* I4 = (const int4*)(igng + (size_t)b * NN);
#pragma unroll
  for (int j = 0; j < 4; j++) {
    u32 e0 = base + j * 1024 + tid * 4;
    int4 pv = P4[e0 >> 2];
    int4 nv = Q4[e0 >> 2];
    int4 iv = I4[e0 >> 2];
#pragma unroll
    for (int m = 0; m < 4; m++) {
      u32 e = e0 + m;
      int p = (&pv.x)[m] != 0, n = (&nv.x)[m] != 0, ig = (&iv.x)[m] != 0;
      u32 label = ((p | n) && !ig) ? (p ? 1u : 2u) : 0u;
      u32 k1 = tf_bits(sk[0], sk[1], e);
      u32 bin = k1 >> 24;
      rr[j * 4 + m] = atomicAdd(&hist[bin], 1u);
      recs[j * 4 + m] = ((u64)k1 << 19) | ((u64)e << 2) | (u64)label;
    }
  }
  __syncthreads();
  if (tid < NCOARSE) stmp[tid] = hist[tid];
  __syncthreads();
  for (int off = 1; off < NCOARSE; off <<= 1) {
    u32 t = 0;
    if (tid < NCOARSE && tid >= off) t = stmp[tid - off];
    __syncthreads();
    if (tid < NCOARSE) stmp[tid] += t;
    __syncthreads();
  }
  if (tid < NCOARSE) lstart[tid] = stmp[tid] - hist[tid];
  __syncthreads();
#pragma unroll
  for (int j = 0; j < 16; j++) {
    u32 bin = (u32)(recs[j] >> 43);
    staged[lstart[bin] + rr[j]] = recs[j];
  }
  if (tid < NCOARSE) {
    u32 c = hist[tid];
    gbase[tid] = c ? atomicAdd(&cursor[(size_t)g * NCOARSE + tid], c) : 0u;
  }
  __syncthreads();
  u64* bn = binned + (size_t)g * NCOARSE * SLOT;
  for (int s = tid; s < CHUNK; s += 256) {
    u64 v = staged[s];
    u32 bin = (u32)(v >> 43);
    u32 dst = bin * SLOT + gbase[bin] + ((u32)s - lstart[bin]);
    bn[dst] = v;
  }
}

// exclusive scan of 256 bucket counts per batch -> starts
__global__ __launch_bounds__(256) void scanB_kernel(const u32* __restrict__ cursor, u32* __restrict__ starts) {
  __shared__ u32 stmp[NCOARSE];
  __shared__ u32 cnts[NCOARSE];
  int g = blockIdx.x, tid = threadIdx.x;
  u32 v = cursor[(size_t)g * NCOARSE + tid];
  cnts[tid] = v; stmp[tid] = v;
  __syncthreads();
  for (int off = 1; off < NCOARSE; off <<= 1) {
    u32 t = (tid >= off) ? stmp[tid - off] : 0u;
    __syncthreads();
    stmp[tid] += t;
    __syncthreads();
  }
  starts[(size_t)g * NCOARSE + tid] = stmp[tid] - cnts[tid];
}

// One block handles 8 buckets. Counting sub-sort with 1024 sub-bins (k1 bits
// 23..14 = key bits 42..33; Poisson(1)), pair-owned shfl-scan, LDS scatter,
// then ELEMENT-WISE exact rank: thread of slot i ranks key[i] within its
// sub-bin (h~1; wave-max ~4 — vs R7's per-sub-bin loop at wave-max h^2 ~49,
// which was the 66% VALUBusy). Writes EL[p1] = k2<<32|e<<2|label.
__global__ __launch_bounds__(512) void passB_kernel(const u32* __restrict__ cursor, const u32* __restrict__ starts,
                                                    const u64* __restrict__ binned, u64* __restrict__ EL,
                                                    u32* __restrict__ posh, u32* __restrict__ negh, int batch0) {
  __shared__ u32 sk2[2];
  __shared__ u64 keys[SLOT];
  __shared__ u32 hist[NSUB];
  __shared__ u32 sstart[NSUB];
  __shared__ u32 wtot[8];
  __shared__ u32 lpos[NCOARSE], lneg[NCOARSE];
  int g = blockIdx.y;
  int tid = threadIdx.x;
  if (tid == 0) {
    u32 a, c;
    batch_round_key(batch0 + g, 2, a, c); sk2[0] = a; sk2[1] = c;
  }
  if (tid < NCOARSE) { lpos[tid] = 0; lneg[tid] = 0; }
  __syncthreads();
  const u64* bn = binned + (size_t)g * NCOARSE * SLOT;
  u64* el = EL + (size_t)g * NN;
  for (int q = 0; q < 8; q++) {
    u32 bin = blockIdx.x * 8 + q;
    u32 cnt = cursor[(size_t)g * NCOARSE + bin];
    if (cnt > SLOT) cnt = SLOT;
    u32 start = starts[(size_t)g * NCOARSE + bin];
    hist[tid] = 0; hist[tid + 512] = 0;
    __syncthreads();
    // load full keys; sub-bin histogram; keep key/ticket in registers
    u64 mykey[2]; u32 mysr[2];
#pragma unroll
    for (int t = 0; t < 2; t++) {
      int i = tid + t * 512;
      if (i < (int)cnt) {
        u64 key = bn[bin * SLOT + i];
        u32 sub = (u32)(key >> 33) & 0x3FFu;
        u32 r = atomicAdd(&hist[sub], 1u);
        mykey[t] = key;
        mysr[t] = (sub << 10) | r;
      } else {
        mysr[t] = 0xFFFFFFFFu;
      }
    }
    __syncthreads();
    // exclusive scan over 1024 sub-bins; thread owns bins 2t, 2t+1
    u32 h0 = hist[2 * tid], h1 = hist[2 * tid + 1];
    u32 s = h0 + h1;
    u32 v = s;
#pragma unroll
    for (int off = 1; off < 64; off <<= 1) {
      u32 t2 = __shfl_up(v, off, 64);
      if ((tid & 63) >= off) v += t2;
    }
    if ((tid & 63) == 63) wtot[tid >> 6] = v;
    __syncthreads();
    u32 woff = 0;
    for (int w = 0; w < (tid >> 6); w++) woff += wtot[w];
    u32 excl = v + woff - s;
    sstart[2 * tid] = excl;
    sstart[2 * tid + 1] = excl + h0;
    __syncthreads();
    // scatter into sub-bin-grouped order (slots 0..cnt-1 exactly filled)
#pragma unroll
    for (int t = 0; t < 2; t++) {
      if (mysr[t] != 0xFFFFFFFFu)
        keys[sstart[mysr[t] >> 10] + (mysr[t] & 0x3FFu)] = mykey[t];
    }
    __syncthreads();
    // element-wise exact stable rank (full u64 compare; e unique)
#pragma unroll
    for (int t = 0; t < 2; t++) {
      int i = tid + t * 512;
      if (i < (int)cnt) {
        u64 ki = keys[i];
        u32 sub = (u32)(ki >> 33) & 0x3FFu;
        u32 s0 = sstart[sub], h = hist[sub];
        u32 r = 0;
        for (u32 j = s0; j < s0 + h; j++) {
          if (keys[j] < ki) r++;
        }
        u32 p1 = start + s0 + r;
        u32 e = (u32)(ki >> 2) & EMASK17;
        u32 label = (u32)ki & 3u;
        u32 k2 = 0;
        if (label) {
          k2 = tf_bits(sk2[0], sk2[1], p1);
          if (label == 1) atomicAdd(&lpos[k2 >> 24], 1u);
          else atomicAdd(&lneg[k2 >> 24], 1u);
        }
        el[p1] = ((u64)k2 << 32) | ((u64)e << 2) | (u64)label;
      }
    }
    __syncthreads();
  }
  if (tid < NCOARSE) {
    if (lpos[tid]) atomicAdd(&posh[(size_t)g * NCOARSE + tid], lpos[tid]);
  } else if (tid < 2 * NCOARSE) {
    int t = tid - NCOARSE;
    if (lneg[t]) atomicAdd(&negh[(size_t)g * NCOARSE + t], lneg[t]);
  }
}

// Per batch: qp = min(128,np), qn = 512-qp; threshold bins over 256-bin hists.
__global__ __launch_bounds__(256) void threshold_kernel(const u32* __restrict__ posh,
                                                        const u32* __restrict__ negh,
                                                        u32* __restrict__ params) {
  int g = blockIdx.x, tid = threadIdx.x;
  __shared__ u32 rp[NCOARSE], rn[NCOARSE];
  rp[tid] = posh[(size_t)g * NCOARSE + tid];
  rn[tid] = negh[(size_t)g * NCOARSE + tid];
  __syncthreads();
  if (tid == 0) {
    u32 np = 0;
    for (int i = 0; i < NCOARSE; i++) np += rp[i];
    u32 qp = np < 128 ? np : 128;
    u32 qn = 512 - qp;
    u32 tp = 256;
    if (qp > 0) {
      u32 cum = 0;
      for (int i = 255; i >= 0; i--) { cum += rp[i]; if (cum >= qp) { tp = (u32)i; break; } }
    }
    u32 tn = 0, cum = 0;
    for (int i = 255; i >= 0; i--) { cum += rn[i]; if (cum >= qn) { tn = (u32)i; break; } }
    u32* pr = params + (size_t)g * 4;
    pr[0] = tp; pr[1] = tn; pr[2] = qp; pr[3] = qn;
  }
}

// Memory-bound threshold filter over EL (k2 precomputed by passB — no threefry).
// Grid (32, G) = 2048 wgs (CP dispatch-rate floor ~60-95 wg/us, R2-R6).
__global__ __launch_bounds__(256) void collect_kernel(const u64* __restrict__ EL, const u32* __restrict__ params,
                                                      u32* __restrict__ cnt, u64* __restrict__ poskey,
                                                      u32* __restrict__ posval, u64* __restrict__ negkey,
                                                      u32* __restrict__ negval, int batch0) {
  __shared__ u32 sp[2];
  int g = blockIdx.y;
  if (threadIdx.x == 0) {
    const u32* pr = params + (size_t)g * 4; sp[0] = pr[0]; sp[1] = pr[1];
  }
  __syncthreads();
  const u64* el = EL + (size_t)g * NN;
#pragma unroll
  for (int c = 0; c < 16; c++) {
    u32 p1 = blockIdx.x * CHUNK + c * 256 + threadIdx.x;
    u64 v = el[p1];
    u32 label = (u32)v & 3u;
    if (!label) continue;
    u32 k2 = (u32)(v >> 32);
    u32 val = ((u32)(v >> 2) & EMASK17) | (label << 17);
    if (label == 1) {
      if ((k2 >> 24) >= sp[0]) {
        u32 s = atomicAdd(&cnt[(size_t)g * 2], 1u);
        if (s < CAP) { poskey[(size_t)g * CAP + s] = ((u64)k2 << 32) | p1; posval[(size_t)g * CAP + s] = val; }
      }
    } else {
      if ((k2 >> 24) >= sp[1]) {
        u32 s = atomicAdd(&cnt[(size_t)g * 2 + 1], 1u);
        if (s < CAP) { negkey[(size_t)g * CAP + s] = ((u64)k2 << 32) | p1; negval[(size_t)g * CAP + s] = val; }
      }
    }
  }
}

// Per batch: exact top-qp / top-qn by (k2,p1) desc over collected, then 512
// ascending index sort -> output.
__global__ __launch_bounds__(1024) void select_final_kernel(const u32* __restrict__ params,
                                                            const u32* __restrict__ cnt,
                                                            const u64* __restrict__ poskey,
                                                            const u32* __restrict__ posval,
                                                            const u64* __restrict__ negkey,
                                                            const u32* __restrict__ negval,
                                                            int* __restrict__ out, int batch0) {
  int g = blockIdx.x, tid = threadIdx.x, b = batch0 + g;
  __shared__ u64 skey[1024];
  __shared__ u32 sval[1024];
  __shared__ int sel[512];
  const u32* pr = params + (size_t)g * 4;
  u32 qp = pr[2], qn = pr[3];
  u32 cp = cnt[(size_t)g * 2]; if (cp > CAP) cp = CAP;
  u32 cn = cnt[(size_t)g * 2 + 1]; if (cn > CAP) cn = CAP;
  if (tid < 512) sel[tid] = 0;

  skey[tid] = (tid < (int)cp) ? poskey[(size_t)g * CAP + tid] : 0ull;
  sval[tid] = (tid < (int)cp) ? posval[(size_t)g * CAP + tid] : 0u;
  __syncthreads();
  for (int k = 2; k <= 1024; k <<= 1)
    for (int s = k >> 1; s > 0; s >>= 1) {
      if (tid < 512) {
        int i = ((tid & ~(s - 1)) << 1) | (tid & (s - 1));
        int j = i | s;
        bool up = ((i & k) == 0);
        if ((skey[i] < skey[j]) == up) {
          u64 tk = skey[i]; skey[i] = skey[j]; skey[j] = tk;
          u32 tv = sval[i]; sval[i] = sval[j]; sval[j] = tv;
        }
      }
      __syncthreads();
    }
  if (tid < (int)qp) sel[tid] = (int)(sval[tid] & EMASK17);
  __syncthreads();

  skey[tid] = (tid < (int)cn) ? negkey[(size_t)g * CAP + tid] : 0ull;
  sval[tid] = (tid < (int)cn) ? negval[(size_t)g * CAP + tid] : 0u;
  __syncthreads();
  for (int k = 2; k <= 1024; k <<= 1)
    for (int s = k >> 1; s > 0; s >>= 1) {
      if (tid < 512) {
        int i = ((tid & ~(s - 1)) << 1) | (tid & (s - 1));
        int j = i | s;
        bool up = ((i & k) == 0);
        if ((skey[i] < skey[j]) == up) {
          u64 tk = skey[i]; skey[i] = skey[j]; skey[j] = tk;
          u32 tv = sval[i]; sval[i] = sval[j]; sval[j] = tv;
        }
      }
      __syncthreads();
    }
  if (tid < (int)qn) sel[qp + tid] = (int)(sval[tid] & EMASK17);
  __syncthreads();

  for (int k = 2; k <= 512; k <<= 1)
    for (int s = k >> 1; s > 0; s >>= 1) {
      if (tid < 256) {
        int i = ((tid & ~(s - 1)) << 1) | (tid & (s - 1));
        int j = i | s;
        bool up = ((i & k) == 0);
        int a = sel[i], c = sel[j];
        if ((a > c) == up) { sel[i] = c; sel[j] = a; }
      }
      __syncthreads();
    }
  if (tid < 512) out[(size_t)b * 512 + tid] = sel[tid];
}

extern "C" void kernel_launch(void* const* d_in, const int* in_sizes, int n_in,
                              void* d_out, int out_size, void* d_ws, size_t ws_size,
                              hipStream_t stream) {
  const int* pos = (const int*)d_in[0];
  const int* neg = (const int*)d_in[1];
  const int* ign = (const int*)d_in[2];
  int* out = (int*)d_out;

  size_t zeroPer = (NCOARSE * 3 + 2) * 4;
  size_t perBatch = zeroPer + (size_t)NCOARSE * SLOT * 8 + (size_t)NN * 8 + NCOARSE * 4 + 16 +
                    (size_t)CAP * (8 + 8 + 4 + 4);
  int G = (int)(ws_size / perBatch);
  if (G > BATCH) G = BATCH;
  if (G < 1) G = 1;

  char* p = (char*)d_ws;
  u32* cursor = (u32*)p;            p += (size_t)G * NCOARSE * 4;
  u32* posh = (u32*)p;              p += (size_t)G * NCOARSE * 4;
  u32* negh = (u32*)p;              p += (size_t)G * NCOARSE * 4;
  u32* cnt = (u32*)p;               p += (size_t)G * 2 * 4;
  size_t zeroBytes = (size_t)p - (size_t)d_ws;
  u64* binned = (u64*)p;            p += (size_t)G * NCOARSE * SLOT * 8;
  u64* EL = (u64*)p;                p += (size_t)G * NN * 8;
  u32* starts = (u32*)p;            p += (size_t)G * NCOARSE * 4;
  u32* params = (u32*)p;            p += (size_t)G * 4 * 4;
  u64* poskey = (u64*)p;            p += (size_t)G * CAP * 8;
  u64* negkey = (u64*)p;            p += (size_t)G * CAP * 8;
  u32* posval = (u32*)p;            p += (size_t)G * CAP * 4;
  u32* negval = (u32*)p;            p += (size_t)G * CAP * 4;

  for (int batch0 = 0; batch0 < BATCH; batch0 += G) {
    int Gi = (BATCH - batch0 < G) ? (BATCH - batch0) : G;
    hipMemsetAsync(d_ws, 0, zeroBytes, stream);
    dim3 gridS(NN / CHUNK, Gi);
    scatterA_kernel<<<gridS, 256, 0, stream>>>(cursor, binned, pos, neg, ign, batch0);
    scanB_kernel<<<Gi, 256, 0, stream>>>(cursor, starts);
    dim3 gridP(NCOARSE / 8, Gi);
    passB_kernel<<<gridP, 512, 0, stream>>>(cursor, starts, binned, EL, posh, negh, batch0);
    threshold_kernel<<<Gi, 256, 0, stream>>>(posh, negh, params);
    dim3 gridC(NN / CHUNK, Gi);
    collect_kernel<<<gridC, 256, 0, stream>>>(EL, params, cnt, poskey, posval, negkey, negval, batch0);
    select_final_kernel<<<Gi, 1024, 0, stream>>>(params, cnt, poskey, posval, negkey, negval, out, batch0);
  }
}

// Round 9
// 256.870 us; speedup vs baseline: 10.8520x; 1.3937x over previous
//
#include <hip/hip_runtime.h>
#include <stdint.h>

#define BATCH 64
#define NN 131072
#define NCOARSE 256
#define SLOT 1024
#define CHUNK 4096
#define NSUB 1024
#define EMASK17 0x1FFFFu
#define CAP 1024
#define CCAP 256

typedef uint32_t u32;
typedef uint64_t u64;

__device__ __forceinline__ u32 rotl32(u32 v, int d) { return (v << d) | (v >> (32 - d)); }

// Exact port of JAX threefry2x32 block cipher
__device__ __forceinline__ void threefry2x32(u32 k0, u32 k1, u32 x0, u32 x1, u32& o0, u32& o1) {
  u32 ks2 = k0 ^ k1 ^ 0x1BD11BDAu;
  x0 += k0; x1 += k1;
#define TF_R(r) { x0 += x1; x1 = rotl32(x1, r); x1 ^= x0; }
  TF_R(13) TF_R(15) TF_R(26) TF_R(6)
  x0 += k1;  x1 += ks2 + 1u;
  TF_R(17) TF_R(29) TF_R(16) TF_R(24)
  x0 += ks2; x1 += k0 + 2u;
  TF_R(13) TF_R(15) TF_R(26) TF_R(6)
  x0 += k0;  x1 += k1 + 3u;
  TF_R(17) TF_R(29) TF_R(16) TF_R(24)
  x0 += k1;  x1 += ks2 + 4u;
  TF_R(13) TF_R(15) TF_R(26) TF_R(6)
  x0 += ks2; x1 += k0 + 5u;
#undef TF_R
  o0 = x0; o1 = x1;
}

// threefry_partitionable: bits[i] = o0 ^ o1 of cipher(key, (0, i))
__device__ __forceinline__ u32 tf_bits(u32 k0, u32 k1, u32 i) {
  u32 o0, o1;
  threefry2x32(k0, k1, 0u, i, o0, o1);
  return o0 ^ o1;
}

// kb = cipher((0,42),(0,b)); round1 sub = cipher(kb,(0,1));
// round2 sub = cipher(cipher(kb,(0,0)),(0,1))
__device__ void batch_round_key(int b, int round, u32& rk0, u32& rk1) {
  u32 kb0, kb1;
  threefry2x32(0u, 42u, 0u, (u32)b, kb0, kb1);
  if (round == 1) { threefry2x32(kb0, kb1, 0u, 1u, rk0, rk1); return; }
  u32 c0, c1;
  threefry2x32(kb0, kb1, 0u, 0u, c0, c1);
  threefry2x32(c0, c1, 0u, 1u, rk0, rk1);
}

// Coarse bucket scatter with LDS staging: bins by k1>>24 into 1024-slot regions.
// Stores the FULL u64 sort key (k1<<19 | e<<2 | label) so passB never recomputes k1.
__global__ __launch_bounds__(256) void scatterA_kernel(u32* __restrict__ cursor, u64* __restrict__ binned,
                                                       const int* __restrict__ posg, const int* __restrict__ negg,
                                                       const int* __restrict__ igng, int batch0) {
  __shared__ u32 sk[2];
  __shared__ u32 hist[NCOARSE];
  __shared__ u32 lstart[NCOARSE];
  __shared__ u32 gbase[NCOARSE];
  __shared__ u64 staged[CHUNK];
  __shared__ u32 stmp[NCOARSE];
  int g = blockIdx.y;
  int b = batch0 + g;
  int tid = threadIdx.x;
  if (tid == 0) { u32 k0, k1; batch_round_key(b, 1, k0, k1); sk[0] = k0; sk[1] = k1; }
  if (tid < NCOARSE) hist[tid] = 0;
  __syncthreads();
  u32 base = blockIdx.x * CHUNK;
  u64 recs[16]; u32 rr[16];
  const int4* P4 = (const int4*)(posg + (size_t)b * NN);
  const int4* Q4 = (const int4*)(negg + (size_t)b * NN);
  const int4* I4 = (const int4*)(igng + (size_t)b * NN);
#pragma unroll
  for (int j = 0; j < 4; j++) {
    u32 e0 = base + j * 1024 + tid * 4;
    int4 pv = P4[e0 >> 2];
    int4 nv = Q4[e0 >> 2];
    int4 iv = I4[e0 >> 2];
#pragma unroll
    for (int m = 0; m < 4; m++) {
      u32 e = e0 + m;
      int p = (&pv.x)[m] != 0, n = (&nv.x)[m] != 0, ig = (&iv.x)[m] != 0;
      u32 label = ((p | n) && !ig) ? (p ? 1u : 2u) : 0u;
      u32 k1 = tf_bits(sk[0], sk[1], e);
      u32 bin = k1 >> 24;
      rr[j * 4 + m] = atomicAdd(&hist[bin], 1u);
      recs[j * 4 + m] = ((u64)k1 << 19) | ((u64)e << 2) | (u64)label;
    }
  }
  __syncthreads();
  if (tid < NCOARSE) stmp[tid] = hist[tid];
  __syncthreads();
  for (int off = 1; off < NCOARSE; off <<= 1) {
    u32 t = 0;
    if (tid < NCOARSE && tid >= off) t = stmp[tid - off];
    __syncthreads();
    if (tid < NCOARSE) stmp[tid] += t;
    __syncthreads();
  }
  if (tid < NCOARSE) lstart[tid] = stmp[tid] - hist[tid];
  __syncthreads();
#pragma unroll
  for (int j = 0; j < 16; j++) {
    u32 bin = (u32)(recs[j] >> 43);
    staged[lstart[bin] + rr[j]] = recs[j];
  }
  if (tid < NCOARSE) {
    u32 c = hist[tid];
    gbase[tid] = c ? atomicAdd(&cursor[(size_t)g * NCOARSE + tid], c) : 0u;
  }
  __syncthreads();
  u64* bn = binned + (size_t)g * NCOARSE * SLOT;
  for (int s = tid; s < CHUNK; s += 256) {
    u64 v = staged[s];
    u32 bin = (u32)(v >> 43);
    u32 dst = bin * SLOT + gbase[bin] + ((u32)s - lstart[bin]);
    bn[dst] = v;
  }
}

// exclusive scan of 256 bucket counts per batch -> starts
__global__ __launch_bounds__(256) void scanB_kernel(const u32* __restrict__ cursor, u32* __restrict__ starts) {
  __shared__ u32 stmp[NCOARSE];
  __shared__ u32 cnts[NCOARSE];
  int g = blockIdx.x, tid = threadIdx.x;
  u32 v = cursor[(size_t)g * NCOARSE + tid];
  cnts[tid] = v; stmp[tid] = v;
  __syncthreads();
  for (int off = 1; off < NCOARSE; off <<= 1) {
    u32 t = (tid >= off) ? stmp[tid - off] : 0u;
    __syncthreads();
    stmp[tid] += t;
    __syncthreads();
  }
  starts[(size_t)g * NCOARSE + tid] = stmp[tid] - cnts[tid];
}

// One block handles 8 buckets. Counting sub-sort with 1024 sub-bins, pair-owned
// shfl-scan, LDS scatter, element-wise exact rank. EL[p1] = k2<<32|e<<2|label.
__global__ __launch_bounds__(512) void passB_kernel(const u32* __restrict__ cursor, const u32* __restrict__ starts,
                                                    const u64* __restrict__ binned, u64* __restrict__ EL,
                                                    u32* __restrict__ posh, u32* __restrict__ negh, int batch0) {
  __shared__ u32 sk2[2];
  __shared__ u64 keys[SLOT];
  __shared__ u32 hist[NSUB];
  __shared__ u32 sstart[NSUB];
  __shared__ u32 wtot[8];
  __shared__ u32 lpos[NCOARSE], lneg[NCOARSE];
  int g = blockIdx.y;
  int tid = threadIdx.x;
  if (tid == 0) {
    u32 a, c;
    batch_round_key(batch0 + g, 2, a, c); sk2[0] = a; sk2[1] = c;
  }
  if (tid < NCOARSE) { lpos[tid] = 0; lneg[tid] = 0; }
  __syncthreads();
  const u64* bn = binned + (size_t)g * NCOARSE * SLOT;
  u64* el = EL + (size_t)g * NN;
  for (int q = 0; q < 8; q++) {
    u32 bin = blockIdx.x * 8 + q;
    u32 cnt = cursor[(size_t)g * NCOARSE + bin];
    if (cnt > SLOT) cnt = SLOT;
    u32 start = starts[(size_t)g * NCOARSE + bin];
    hist[tid] = 0; hist[tid + 512] = 0;
    __syncthreads();
    u64 mykey[2]; u32 mysr[2];
#pragma unroll
    for (int t = 0; t < 2; t++) {
      int i = tid + t * 512;
      if (i < (int)cnt) {
        u64 key = bn[bin * SLOT + i];
        u32 sub = (u32)(key >> 33) & 0x3FFu;
        u32 r = atomicAdd(&hist[sub], 1u);
        mykey[t] = key;
        mysr[t] = (sub << 10) | r;
      } else {
        mysr[t] = 0xFFFFFFFFu;
      }
    }
    __syncthreads();
    u32 h0 = hist[2 * tid], h1 = hist[2 * tid + 1];
    u32 s = h0 + h1;
    u32 v = s;
#pragma unroll
    for (int off = 1; off < 64; off <<= 1) {
      u32 t2 = __shfl_up(v, off, 64);
      if ((tid & 63) >= off) v += t2;
    }
    if ((tid & 63) == 63) wtot[tid >> 6] = v;
    __syncthreads();
    u32 woff = 0;
    for (int w = 0; w < (tid >> 6); w++) woff += wtot[w];
    u32 excl = v + woff - s;
    sstart[2 * tid] = excl;
    sstart[2 * tid + 1] = excl + h0;
    __syncthreads();
#pragma unroll
    for (int t = 0; t < 2; t++) {
      if (mysr[t] != 0xFFFFFFFFu)
        keys[sstart[mysr[t] >> 10] + (mysr[t] & 0x3FFu)] = mykey[t];
    }
    __syncthreads();
#pragma unroll
    for (int t = 0; t < 2; t++) {
      int i = tid + t * 512;
      if (i < (int)cnt) {
        u64 ki = keys[i];
        u32 sub = (u32)(ki >> 33) & 0x3FFu;
        u32 s0 = sstart[sub], h = hist[sub];
        u32 r = 0;
        for (u32 j = s0; j < s0 + h; j++) {
          if (keys[j] < ki) r++;
        }
        u32 p1 = start + s0 + r;
        u32 e = (u32)(ki >> 2) & EMASK17;
        u32 label = (u32)ki & 3u;
        u32 k2 = 0;
        if (label) {
          k2 = tf_bits(sk2[0], sk2[1], p1);
          if (label == 1) atomicAdd(&lpos[k2 >> 24], 1u);
          else atomicAdd(&lneg[k2 >> 24], 1u);
        }
        el[p1] = ((u64)k2 << 32) | ((u64)e << 2) | (u64)label;
      }
    }
    __syncthreads();
  }
  if (tid < NCOARSE) {
    if (lpos[tid]) atomicAdd(&posh[(size_t)g * NCOARSE + tid], lpos[tid]);
  } else if (tid < 2 * NCOARSE) {
    int t = tid - NCOARSE;
    if (lneg[t]) atomicAdd(&negh[(size_t)g * NCOARSE + t], lneg[t]);
  }
}

// Per batch: qp = min(128,np), qn = 512-qp; threshold bins over 256-bin hists.
__global__ __launch_bounds__(256) void threshold_kernel(const u32* __restrict__ posh,
                                                        const u32* __restrict__ negh,
                                                        u32* __restrict__ params) {
  int g = blockIdx.x, tid = threadIdx.x;
  __shared__ u32 rp[NCOARSE], rn[NCOARSE];
  rp[tid] = posh[(size_t)g * NCOARSE + tid];
  rn[tid] = negh[(size_t)g * NCOARSE + tid];
  __syncthreads();
  if (tid == 0) {
    u32 np = 0;
    for (int i = 0; i < NCOARSE; i++) np += rp[i];
    u32 qp = np < 128 ? np : 128;
    u32 qn = 512 - qp;
    u32 tp = 256;
    if (qp > 0) {
      u32 cum = 0;
      for (int i = 255; i >= 0; i--) { cum += rp[i]; if (cum >= qp) { tp = (u32)i; break; } }
    }
    u32 tn = 0, cum = 0;
    for (int i = 255; i >= 0; i--) { cum += rn[i]; if (cum >= qn) { tn = (u32)i; break; } }
    u32* pr = params + (size_t)g * 4;
    pr[0] = tp; pr[1] = tn; pr[2] = qp; pr[3] = qn;
  }
}

// Threshold filter over EL with BLOCK-LOCAL aggregation. R8 showed 113us
// invariant to cache warmth: ~30k returning device atomics to one 256B cnt
// region serialized at the memory-side cache. Now: LDS staging + 2 global
// atomics per block, cnt strided 64B/batch so batches hit different lines.
__global__ __launch_bounds__(256) void collect_kernel(const u64* __restrict__ EL, const u32* __restrict__ params,
                                                      u32* __restrict__ cnt, u64* __restrict__ poskey,
                                                      u32* __restrict__ posval, u64* __restrict__ negkey,
                                                      u32* __restrict__ negval, int batch0) {
  __shared__ u32 sp[2];
  __shared__ u32 lcnt[2];
  __shared__ u32 lbase[2];
  __shared__ u64 skey[2][CCAP];
  __shared__ u32 sval[2][CCAP];
  int g = blockIdx.y;
  int tid = threadIdx.x;
  if (tid == 0) {
    const u32* pr = params + (size_t)g * 4; sp[0] = pr[0]; sp[1] = pr[1];
    lcnt[0] = 0; lcnt[1] = 0;
  }
  __syncthreads();
  const u64* el = EL + (size_t)g * NN;
#pragma unroll
  for (int c = 0; c < 16; c++) {
    u32 p1 = blockIdx.x * CHUNK + c * 256 + tid;
    u64 v = el[p1];
    u32 label = (u32)v & 3u;
    if (!label) continue;
    u32 k2 = (u32)(v >> 32);
    int li = (int)label - 1;  // 0=pos, 1=neg
    if ((k2 >> 24) >= sp[li]) {
      u32 val = ((u32)(v >> 2) & EMASK17) | (label << 17);
      u32 r = atomicAdd(&lcnt[li], 1u);
      if (r < CCAP) {
        skey[li][r] = (v & 0xFFFFFFFF00000000ull) | p1;
        sval[li][r] = val;
      } else {  // overflow fallback (exactness preserved; ~never taken)
        u32 s = atomicAdd(&cnt[(size_t)g * 16 + li], 1u);
        if (s < CAP) {
          if (li == 0) { poskey[(size_t)g * CAP + s] = ((u64)k2 << 32) | p1; posval[(size_t)g * CAP + s] = val; }
          else { negkey[(size_t)g * CAP + s] = ((u64)k2 << 32) | p1; negval[(size_t)g * CAP + s] = val; }
        }
      }
    }
  }
  __syncthreads();
  if (tid < 2) {
    u32 n = lcnt[tid]; if (n > CCAP) n = CCAP;
    lbase[tid] = n ? atomicAdd(&cnt[(size_t)g * 16 + tid], n) : 0u;
  }
  __syncthreads();
#pragma unroll
  for (int li = 0; li < 2; li++) {
    u32 n = lcnt[li]; if (n > CCAP) n = CCAP;
    u64* gk = li ? negkey : poskey;
    u32* gv = li ? negval : posval;
    for (u32 i = tid; i < n; i += 256) {
      u32 s = lbase[li] + i;
      if (s < CAP) { gk[(size_t)g * CAP + s] = skey[li][i]; gv[(size_t)g * CAP + s] = sval[li][i]; }
    }
  }
}

// Per batch: exact top-qp / top-qn by (k2,p1) desc over collected, then 512
// ascending index sort -> output.
__global__ __launch_bounds__(1024) void select_final_kernel(const u32* __restrict__ params,
                                                            const u32* __restrict__ cnt,
                                                            const u64* __restrict__ poskey,
                                                            const u32* __restrict__ posval,
                                                            const u64* __restrict__ negkey,
                                                            const u32* __restrict__ negval,
                                                            int* __restrict__ out, int batch0) {
  int g = blockIdx.x, tid = threadIdx.x, b = batch0 + g;
  __shared__ u64 skey[1024];
  __shared__ u32 sval[1024];
  __shared__ int sel[512];
  const u32* pr = params + (size_t)g * 4;
  u32 qp = pr[2], qn = pr[3];
  u32 cp = cnt[(size_t)g * 16]; if (cp > CAP) cp = CAP;
  u32 cn = cnt[(size_t)g * 16 + 1]; if (cn > CAP) cn = CAP;
  if (tid < 512) sel[tid] = 0;

  skey[tid] = (tid < (int)cp) ? poskey[(size_t)g * CAP + tid] : 0ull;
  sval[tid] = (tid < (int)cp) ? posval[(size_t)g * CAP + tid] : 0u;
  __syncthreads();
  for (int k = 2; k <= 1024; k <<= 1)
    for (int s = k >> 1; s > 0; s >>= 1) {
      if (tid < 512) {
        int i = ((tid & ~(s - 1)) << 1) | (tid & (s - 1));
        int j = i | s;
        bool up = ((i & k) == 0);
        if ((skey[i] < skey[j]) == up) {
          u64 tk = skey[i]; skey[i] = skey[j]; skey[j] = tk;
          u32 tv = sval[i]; sval[i] = sval[j]; sval[j] = tv;
        }
      }
      __syncthreads();
    }
  if (tid < (int)qp) sel[tid] = (int)(sval[tid] & EMASK17);
  __syncthreads();

  skey[tid] = (tid < (int)cn) ? negkey[(size_t)g * CAP + tid] : 0ull;
  sval[tid] = (tid < (int)cn) ? negval[(size_t)g * CAP + tid] : 0u;
  __syncthreads();
  for (int k = 2; k <= 1024; k <<= 1)
    for (int s = k >> 1; s > 0; s >>= 1) {
      if (tid < 512) {
        int i = ((tid & ~(s - 1)) << 1) | (tid & (s - 1));
        int j = i | s;
        bool up = ((i & k) == 0);
        if ((skey[i] < skey[j]) == up) {
          u64 tk = skey[i]; skey[i] = skey[j]; skey[j] = tk;
          u32 tv = sval[i]; sval[i] = sval[j]; sval[j] = tv;
        }
      }
      __syncthreads();
    }
  if (tid < (int)qn) sel[qp + tid] = (int)(sval[tid] & EMASK17);
  __syncthreads();

  for (int k = 2; k <= 512; k <<= 1)
    for (int s = k >> 1; s > 0; s >>= 1) {
      if (tid < 256) {
        int i = ((tid & ~(s - 1)) << 1) | (tid & (s - 1));
        int j = i | s;
        bool up = ((i & k) == 0);
        int a = sel[i], c = sel[j];
        if ((a > c) == up) { sel[i] = c; sel[j] = a; }
      }
      __syncthreads();
    }
  if (tid < 512) out[(size_t)b * 512 + tid] = sel[tid];
}

extern "C" void kernel_launch(void* const* d_in, const int* in_sizes, int n_in,
                              void* d_out, int out_size, void* d_ws, size_t ws_size,
                              hipStream_t stream) {
  const int* pos = (const int*)d_in[0];
  const int* neg = (const int*)d_in[1];
  const int* ign = (const int*)d_in[2];
  int* out = (int*)d_out;

  // zero region: cursor 1KB + posh 1KB + negh 1KB + cnt 64B (strided) per batch
  size_t zeroPer = (NCOARSE * 3 + 16) * 4;
  size_t perBatch = zeroPer + (size_t)NCOARSE * SLOT * 8 + (size_t)NN * 8 + NCOARSE * 4 + 16 +
                    (size_t)CAP * (8 + 8 + 4 + 4);
  int G = (int)(ws_size / perBatch);
  if (G > BATCH) G = BATCH;
  if (G < 1) G = 1;

  char* p = (char*)d_ws;
  u32* cursor = (u32*)p;            p += (size_t)G * NCOARSE * 4;
  u32* posh = (u32*)p;              p += (size_t)G * NCOARSE * 4;
  u32* negh = (u32*)p;              p += (size_t)G * NCOARSE * 4;
  u32* cnt = (u32*)p;               p += (size_t)G * 16 * 4;  // 64B stride per batch
  size_t zeroBytes = (size_t)p - (size_t)d_ws;
  u64* binned = (u64*)p;            p += (size_t)G * NCOARSE * SLOT * 8;
  u64* EL = (u64*)p;                p += (size_t)G * NN * 8;
  u32* starts = (u32*)p;            p += (size_t)G * NCOARSE * 4;
  u32* params = (u32*)p;            p += (size_t)G * 4 * 4;
  u64* poskey = (u64*)p;            p += (size_t)G * CAP * 8;
  u64* negkey = (u64*)p;            p += (size_t)G * CAP * 8;
  u32* posval = (u32*)p;            p += (size_t)G * CAP * 4;
  u32* negval = (u32*)p;            p += (size_t)G * CAP * 4;

  for (int batch0 = 0; batch0 < BATCH; batch0 += G) {
    int Gi = (BATCH - batch0 < G) ? (BATCH - batch0) : G;
    hipMemsetAsync(d_ws, 0, zeroBytes, stream);
    dim3 gridS(NN / CHUNK, Gi);
    scatterA_kernel<<<gridS, 256, 0, stream>>>(cursor, binned, pos, neg, ign, batch0);
    scanB_kernel<<<Gi, 256, 0, stream>>>(cursor, starts);
    dim3 gridP(NCOARSE / 8, Gi);
    passB_kernel<<<gridP, 512, 0, stream>>>(cursor, starts, binned, EL, posh, negh, batch0);
    threshold_kernel<<<Gi, 256, 0, stream>>>(posh, negh, params);
    dim3 gridC(NN / CHUNK, Gi);
    collect_kernel<<<gridC, 256, 0, stream>>>(EL, params, cnt, poskey, posval, negkey, negval, batch0);
    select_final_kernel<<<Gi, 1024, 0, stream>>>(params, cnt, poskey, posval, negkey, negval, out, batch0);
  }
}